// Round 12
// baseline (2731.662 us; speedup 1.0000x reference)
//
#include <hip/hip_runtime.h>

// ---------------- problem constants ----------------
constexpr int Nn = 40000;
constexpr int Dd = 128;
constexpr int Rr = 3;
constexpr int Ee = 640000;
constexpr int Ll = 2;
constexpr int Cc = 40;
constexpr int MAXD = 512;
constexpr float BN_EPS = 1e-5f;

// radix sort geometry (permutation keys, 2 batched segments)
constexpr int RB_ELEMS = 1024;
constexpr int RB_NB = (Nn + RB_ELEMS - 1) / RB_ELEMS; // 40 blocks per segment
constexpr int RB_BINS = 256;
constexpr int RB_H = RB_BINS * RB_NB;                 // hist entries per segment

// edge sort geometry
constexpr int EB_ELEMS = 4096;
constexpr int EB_NB = (Ee + EB_ELEMS - 1) / EB_ELEMS; // 157
constexpr int EB_H = 256 * EB_NB;                     // hist entries per array

// histogram geometry
constexpr int HR_BINS = 13334;  // ceil(Nn/3)
constexpr int HR_PAD = 13344;
constexpr int HR_SB = 16;
constexpr int HR_CHUNK = (Ee + HR_SB - 1) / HR_SB;

// ---------------- threefry-2x32 (JAX-compatible) ----------------
__device__ __forceinline__ unsigned rotl32(unsigned x, int d) { return (x << d) | (x >> (32 - d)); }

__device__ void threefry2x32(unsigned k0, unsigned k1, unsigned c0, unsigned c1,
                             unsigned& o0, unsigned& o1) {
  unsigned ks2 = k0 ^ k1 ^ 0x1BD11BDAu;
  unsigned x0 = c0 + k0, x1 = c1 + k1;
#define TFR4(a,b,c,d2) \
  x0 += x1; x1 = rotl32(x1,a);  x1 ^= x0; \
  x0 += x1; x1 = rotl32(x1,b);  x1 ^= x0; \
  x0 += x1; x1 = rotl32(x1,c);  x1 ^= x0; \
  x0 += x1; x1 = rotl32(x1,d2); x1 ^= x0;
  TFR4(13,15,26,6);  x0 += k1;  x1 += ks2 + 1u;
  TFR4(17,29,16,24); x0 += ks2; x1 += k0 + 2u;
  TFR4(13,15,26,6);  x0 += k0;  x1 += k1 + 3u;
  TFR4(17,29,16,24); x0 += k1;  x1 += ks2 + 4u;
  TFR4(13,15,26,6);  x0 += ks2; x1 += k0 + 5u;
#undef TFR4
  o0 = x0; o1 = x1;
}

// batched over 2 segments (seeds seed0, seed1); local index per segment
__global__ void k_genkeys2(unsigned* __restrict__ keys, unsigned seed0, unsigned seed1,
                           int rounds, int* __restrict__ vout, int doIota) {
  int i = blockIdx.x * blockDim.x + threadIdx.x;
  if (i >= 2 * Nn) return;
  int seg = i / Nn, li = i - seg * Nn;
  unsigned seed = seg ? seed1 : seed0;
  unsigned k0 = 0u, k1 = seed, sk0 = 0u, sk1 = 0u;
  for (int rd = 0; rd < rounds; rd++) {
    unsigned a0, a1, b0, b1;
    threefry2x32(k0, k1, 0u, 0u, a0, a1);
    threefry2x32(k0, k1, 0u, 1u, b0, b1);
    sk0 = b0; sk1 = b1;
    k0 = a0; k1 = a1;
  }
  unsigned o0, o1;
  threefry2x32(sk0, sk1, 0u, (unsigned)li, o0, o1);
  keys[i] = o0 ^ o1;
  if (doIota) vout[i] = li;
}

// ---------------- LSD radix sort for permutations (stable, 2 segments) ----------------
__global__ void k_rhist2(const unsigned* __restrict__ keys, int* __restrict__ hist, int shift) {
  __shared__ int lh[RB_BINS];
  int a = blockIdx.x / RB_NB, blk = blockIdx.x % RB_NB;
  const unsigned* src = keys + (size_t)a * Nn;
  int t = threadIdx.x;
  lh[t] = 0;
  __syncthreads();
  int base = blk * RB_ELEMS;
  for (int i = t; i < RB_ELEMS; i += 256) {
    int g = base + i;
    if (g < Nn) atomicAdd(&lh[(src[g] >> shift) & 255], 1);
  }
  __syncthreads();
  hist[(size_t)a * RB_H + t * RB_NB + blk] = lh[t];
}

__device__ void scan_body(const int* cnt, int* off, int n, int items) {
  int t = threadIdx.x;
  int lo = t * items, hi = min(lo + items, n);
  int s = 0;
  for (int i = lo; i < hi; i++) s += cnt[i];
  int lane = t & 63, wid = t >> 6;
  int sc = s;
#pragma unroll
  for (int o = 1; o < 64; o <<= 1) {
    int v = __shfl_up(sc, o);
    if (lane >= o) sc += v;
  }
  __shared__ int wsum[16], woff[16];
  if (lane == 63) wsum[wid] = sc;
  __syncthreads();
  if (t == 0) {
    int a = 0;
    for (int w = 0; w < 16; w++) { woff[w] = a; a += wsum[w]; }
    off[n] = a;
  }
  __syncthreads();
  int run = woff[wid] + sc - s;
  for (int i = lo; i < hi; i++) {
    int v = cnt[i];
    off[i] = run;
    run += v;
  }
}

// 2-segment scan for the perm-sort histograms
__global__ __launch_bounds__(1024) void k_scanP(const int* __restrict__ hist, int* __restrict__ esc) {
  int a = blockIdx.x;
  scan_body(hist + (size_t)a * RB_H, esc + (size_t)a * (RB_H + 1), RB_H, (RB_H + 1023) / 1024);
}

// 6 independent scans (3 csr + 3 csc) in one dispatch
__global__ __launch_bounds__(1024) void k_scan6(const int* __restrict__ odeg, const int* __restrict__ ideg,
                                                int* __restrict__ csr_off, int* __restrict__ csc_off) {
  int b = blockIdx.x;
  const int* cnt = (b < 3) ? (odeg + b * Nn) : (ideg + (b - 3) * Nn);
  int* off = (b < 3) ? (csr_off + b * (Nn + 1)) : (csc_off + (b - 3) * (Nn + 1));
  scan_body(cnt, off, Nn, (Nn + 1023) / 1024);
}

__global__ void k_rscatter2(const unsigned* __restrict__ keys, const int* __restrict__ vals,
                            const int* __restrict__ scanned, int shift,
                            unsigned* __restrict__ okeys, int* __restrict__ ovals) {
  __shared__ int running[RB_BINS];
  __shared__ int wcount[4][RB_BINS];
  __shared__ int dbase[RB_BINS];
  int a = blockIdx.x / RB_NB, blk = blockIdx.x % RB_NB;
  const unsigned* ksrc = keys + (size_t)a * Nn;
  const int* vsrc = vals + (size_t)a * Nn;
  unsigned* kdst = okeys + (size_t)a * Nn;
  int* vdst = ovals + (size_t)a * Nn;
  int t = threadIdx.x;
  int lane = t & 63, w = t >> 6;
  running[t] = 0;
  dbase[t] = scanned[(size_t)a * (RB_H + 1) + t * RB_NB + blk];
  int base = blk * RB_ELEMS;
  for (int rnd = 0; rnd < 4; rnd++) {
#pragma unroll
    for (int q = 0; q < 4; q++) wcount[q][t] = 0;
    __syncthreads();
    int g = base + rnd * 256 + t;
    bool valid = g < Nn;
    unsigned key = valid ? ksrc[g] : 0u;
    int d = (key >> shift) & 255;
    unsigned long long bb = __ballot(valid);
    unsigned long long mask = bb;
#pragma unroll
    for (int k = 0; k < 8; k++) {
      bool b = (d >> k) & 1;
      unsigned long long tt = __ballot(b && valid);
      mask &= b ? tt : ~tt;
    }
    mask &= bb;
    int riw = __popcll(mask & ((1ull << lane) - 1ull));
    int cnt_ = __popcll(mask);
    if (valid && riw == 0) wcount[w][d] = cnt_;
    __syncthreads();
    if (valid) {
      int prior = 0;
#pragma unroll
      for (int ww = 0; ww < 4; ww++) if (ww < w) prior += wcount[ww][d];
      int gp = dbase[d] + running[d] + prior + riw;
      kdst[gp] = key;
      vdst[gp] = vsrc[g];
    }
    __syncthreads();
    running[t] += wcount[0][t] + wcount[1][t] + wcount[2][t] + wcount[3][t];
    __syncthreads();
  }
}

__global__ void k_permrows(const float* __restrict__ src, const int* __restrict__ perm,
                           float* __restrict__ dst) {
  int row = blockIdx.x * 8 + (threadIdx.x >> 5);
  int lane = threadIdx.x & 31;
  if (row >= Nn) return;
  int p = perm[row];
  ((float4*)(dst + (size_t)row * Dd))[lane] = ((const float4*)(src + (size_t)p * Dd))[lane];
}

// ---------------- graph structure (atomic-free histogram) ----------------
__global__ __launch_bounds__(256) void k_hist2(const int* __restrict__ ei, int* __restrict__ partials) {
  __shared__ int lh[HR_BINS];
  int bid = blockIdx.x;  // j*(3*HR_SB) + range*HR_SB + sb
  int sb = bid % HR_SB;
  int range = (bid / HR_SB) % 3;
  int j = bid / (3 * HR_SB);
  int rel = j >> 1, which = j & 1;
  const int* src = ei + (size_t)rel * 2 * Ee + (size_t)which * Ee;
  int lo = range * HR_BINS;
  for (int i = threadIdx.x; i < HR_BINS; i += 256) lh[i] = 0;
  __syncthreads();
  int e0 = sb * HR_CHUNK, e1 = min(e0 + HR_CHUNK, Ee);
  for (int e = e0 + threadIdx.x; e < e1; e += 256) {
    int v = src[e] - lo;
    if (v >= 0 && v < HR_BINS) atomicAdd(&lh[v], 1);
  }
  __syncthreads();
  int* dst = partials + (size_t)bid * HR_PAD;
  for (int i = threadIdx.x; i < HR_BINS; i += 256) dst[i] = lh[i];
}

__global__ void k_hreduce(const int* __restrict__ partials, int* __restrict__ odeg,
                          int* __restrict__ ideg) {
  int idx = blockIdx.x * 256 + threadIdx.x;
  if (idx >= 6 * Nn) return;
  int j = idx / Nn, bin = idx - j * Nn;
  int range = bin / HR_BINS, off = bin - range * HR_BINS;
  const int* p = partials + (size_t)((j * 3 + range) * HR_SB) * HR_PAD + off;
  int sum = 0;
#pragma unroll
  for (int b = 0; b < HR_SB; b++) sum += p[(size_t)b * HR_PAD];
  int rel = j >> 1;
  (j & 1 ? ideg : odeg)[rel * Nn + bin] = sum;
}

__global__ void k_degnorm(const int* __restrict__ odeg, const int* __restrict__ ideg,
                          float* __restrict__ ods, float* __restrict__ ids,
                          int* __restrict__ odix, int* __restrict__ idix) {
  int idx = blockIdx.x * blockDim.x + threadIdx.x;
  if (idx >= Rr * Nn) return;
  int od = odeg[idx], id_ = ideg[idx];
  ods[idx] = od > 0 ? 1.0f / sqrtf((float)od) : 0.0f;
  ids[idx] = id_ > 0 ? 1.0f / sqrtf((float)id_) : 0.0f;
  odix[idx] = od < MAXD - 1 ? od : MAXD - 1;
  idix[idx] = id_ < MAXD - 1 ? id_ : MAXD - 1;
}

// pack edges: pcsr[rel][e] = (row<<16)|col ; pcsc[rel][e] = (col<<16)|row
__global__ void k_pack(const int* __restrict__ ei, unsigned* __restrict__ pcsr,
                       unsigned* __restrict__ pcsc) {
  int idx = blockIdx.x * 256 + threadIdx.x;
  if (idx >= 3 * Ee) return;
  int r = idx / Ee, e = idx - r * Ee;
  const int* base = ei + (size_t)r * 2 * Ee;
  unsigned rw = (unsigned)base[e], cl = (unsigned)base[Ee + e];
  pcsr[idx] = (rw << 16) | cl;
  pcsc[idx] = (cl << 16) | rw;
}

// edge radix: histogram per (array, block)
__global__ __launch_bounds__(256) void k_ehist(const unsigned* __restrict__ pin,
                                               int* __restrict__ hist, int shift) {
  __shared__ int lh[256];
  int a = blockIdx.x / EB_NB, blk = blockIdx.x % EB_NB;
  const unsigned* src = pin + (size_t)a * Ee;
  lh[threadIdx.x] = 0;
  __syncthreads();
  int base = blk * EB_ELEMS;
  for (int i = threadIdx.x; i < EB_ELEMS; i += 256) {
    int g = base + i;
    if (g < Ee) atomicAdd(&lh[(src[g] >> shift) & 255], 1);
  }
  __syncthreads();
  hist[(size_t)a * EB_H + threadIdx.x * EB_NB + blk] = lh[threadIdx.x];
}

// 6 scans of EB_H entries each
__global__ __launch_bounds__(1024) void k_escan6(const int* __restrict__ hist, int* __restrict__ esc) {
  int a = blockIdx.x;
  scan_body(hist + (size_t)a * EB_H, esc + (size_t)a * (EB_H + 1), EB_H, (EB_H + 1023) / 1024);
}

// stable scatter of packed edges (16 rounds of 256)
__global__ __launch_bounds__(256) void k_escatter(const unsigned* __restrict__ pin,
                                                  const int* __restrict__ esc, int shift,
                                                  unsigned* __restrict__ pout) {
  __shared__ int running[256];
  __shared__ int wcount[4][256];
  __shared__ int dbase[256];
  int a = blockIdx.x / EB_NB, blk = blockIdx.x % EB_NB;
  const unsigned* src = pin + (size_t)a * Ee;
  unsigned* dst = pout + (size_t)a * Ee;
  int t = threadIdx.x;
  int lane = t & 63, w = t >> 6;
  running[t] = 0;
  dbase[t] = esc[(size_t)a * (EB_H + 1) + t * EB_NB + blk];
  int base = blk * EB_ELEMS;
  for (int rnd = 0; rnd < 16; rnd++) {
#pragma unroll
    for (int q = 0; q < 4; q++) wcount[q][t] = 0;
    __syncthreads();
    int g = base + rnd * 256 + t;
    bool valid = g < Ee;
    unsigned key = valid ? src[g] : 0u;
    int d = (key >> shift) & 255;
    unsigned long long bb = __ballot(valid);
    unsigned long long mask = bb;
#pragma unroll
    for (int k = 0; k < 8; k++) {
      bool b = (d >> k) & 1;
      unsigned long long tt = __ballot(b && valid);
      mask &= b ? tt : ~tt;
    }
    mask &= bb;
    int riw = __popcll(mask & ((1ull << lane) - 1ull));
    int cnt_ = __popcll(mask);
    if (valid && riw == 0) wcount[w][d] = cnt_;
    __syncthreads();
    if (valid) {
      int prior = 0;
#pragma unroll
      for (int ww = 0; ww < 4; ww++) if (ww < w) prior += wcount[ww][d];
      int gp = dbase[d] + running[d] + prior + riw;
      dst[gp] = key;
    }
    __syncthreads();
    running[t] += wcount[0][t] + wcount[1][t] + wcount[2][t] + wcount[3][t];
    __syncthreads();
  }
}

// ---------------- per-conv kernels ----------------
// aux[n] = (rinv, qo, qi, 0); auxrd[(2r+dir)][n] = (nbr-scale, rinv, q);
// block 0 also zeroes bnsum (and gs for pos convs).
__global__ void k_rowscalar(const float* __restrict__ h, const float* __restrict__ Wfo,
                            const float* __restrict__ Wfi, float4* __restrict__ aux,
                            const float* __restrict__ ods, const float* __restrict__ ids,
                            float4* __restrict__ auxrd,
                            float* __restrict__ bnsum, float* __restrict__ gs) {
  if (blockIdx.x == 0) {
    bnsum[threadIdx.x] = 0.f;
    if (gs != nullptr && threadIdx.x < Dd) gs[threadIdx.x] = 0.f;
  }
  int wid = (blockIdx.x * blockDim.x + threadIdx.x) >> 6;
  int lane = threadIdx.x & 63;
  if (wid >= Nn) return;
  float2 a = ((const float2*)(h + (size_t)wid * Dd))[lane];
  float2 wo = ((const float2*)Wfo)[lane];
  float2 wi = ((const float2*)Wfi)[lane];
  float l1 = fabsf(a.x) + fabsf(a.y);
  float so = a.x * a.x * wo.x + a.y * a.y * wo.y;
  float si = a.x * a.x * wi.x + a.y * a.y * wi.y;
#pragma unroll
  for (int o = 32; o; o >>= 1) {
    l1 += __shfl_xor(l1, o);
    so += __shfl_xor(so, o);
    si += __shfl_xor(si, o);
  }
  if (lane == 0) {
    float ri = 1.0f / (l1 + 1e-12f);
    float qo = ri * ri * so, qi = ri * ri * si;
    aux[wid] = make_float4(ri, qo, qi, 0.f);
#pragma unroll
    for (int r = 0; r < Rr; r++) {
      auxrd[(size_t)(2 * r) * Nn + wid] = make_float4(ids[r * Nn + wid], ri, qo, 0.f);
      auxrd[(size_t)(2 * r + 1) * Nn + wid] = make_float4(ods[r * Nn + wid], ri, qi, 0.f);
    }
  }
}

// both layers' LUTs in one dispatch: luto/luti are [2][MAXD]
__global__ void k_lut2(const float* __restrict__ eo, const float* __restrict__ ei_,
                       const float* __restrict__ W_outf, const float* __restrict__ W_inf,
                       float* __restrict__ luto, float* __restrict__ luti) {
  int wid = (blockIdx.x * blockDim.x + threadIdx.x) >> 6;
  int lane = threadIdx.x & 63;
  if (wid >= 2 * MAXD) return;
  int l = wid >> 9, k = wid & (MAXD - 1);
  float2 a = ((const float2*)(eo + ((size_t)l * MAXD + k) * Dd))[lane];
  float2 b = ((const float2*)(ei_ + ((size_t)l * MAXD + k) * Dd))[lane];
  float2 wo = ((const float2*)(W_outf + l * Dd))[lane];
  float2 wi = ((const float2*)(W_inf + l * Dd))[lane];
  float so = a.x * wo.x + a.y * wo.y;
  float si = b.x * wi.x + b.y * wi.y;
#pragma unroll
  for (int o = 32; o; o >>= 1) { so += __shfl_xor(so, o); si += __shfl_xor(si, o); }
  if (lane == 0) { luto[wid] = so; luti[wid] = si; }
}

// fused gather + score + T accumulation. 256 threads = 4 waves = 2 nodes x 2 dirs.
// PROVEN 2-edge inner loop; per-edge operands packed in one float4 gather.
__global__ __launch_bounds__(256) void k_csrdir3(
    const int* __restrict__ csr_off, const unsigned* __restrict__ pcsr,
    const int* __restrict__ csc_off, const unsigned* __restrict__ pcsc,
    const float* __restrict__ ods_r, const float* __restrict__ ids_r,
    const float4* __restrict__ auxo, const float4* __restrict__ auxi,
    const float4* __restrict__ aux, const float* __restrict__ h,
    const float* __restrict__ Wfo, const float* __restrict__ Wfi,
    const float* __restrict__ luto, const float* __restrict__ luti,
    const int* __restrict__ odix, const int* __restrict__ idix,
    const float* __restrict__ bo, const float* __restrict__ bi,
    const float* __restrict__ taup,
    const float* __restrict__ omask, const float* __restrict__ omaskb,
    const float* __restrict__ imask, const float* __restrict__ imaskb,
    float* __restrict__ Tout, float* __restrict__ Tin,
    float* __restrict__ sco, float* __restrict__ sci,
    float* __restrict__ co_acc, float* __restrict__ ci_acc,
    int first, int is_pos) {
  __shared__ float lq[4], lp[4], lc[4];
  int t = threadIdx.x;
  int wv = t >> 6, lane = t & 63;
  int dir = wv >> 1;
  int n = blockIdx.x * 2 + (wv & 1);
  const int* off = dir ? csc_off : csr_off;
  const unsigned* nbrp = dir ? pcsc : pcsr;
  const float4* auxd = dir ? auxi : auxo;
  float a_self = (dir ? ids_r : ods_r)[n];
  const float* Wf = dir ? Wfi : Wfo;
  int s0 = off[n], s1 = off[n + 1];
  int hl = lane & 31, half = lane >> 5;
  float4 wf4 = ((const float4*)Wf)[hl];
  float4 hn4 = ((const float4*)(h + (size_t)n * Dd))[hl];
  float rn = aux[n].x;
  float4 s = make_float4(0.f, 0.f, 0.f, 0.f);
  float4 pa = make_float4(0.f, 0.f, 0.f, 0.f);
  float qacc = 0.f;
  for (int base = s0; base < s1; base += 64) {
    int eidx = base + lane;
    bool valid = eidx < s1;
    int mi = valid ? (int)(nbrp[eidx] & 0xFFFFu) : 0;
    float4 av = valid ? auxd[mi] : make_float4(0.f, 0.f, 0.f, 0.f);
    int cnt = min(64, s1 - base);
#pragma unroll 4
    for (int j = half; j < cnt; j += 2) {
      int m = __shfl(mi, j);
      float sc = __shfl(av.x, j);
      float rm = __shfl(av.y, j);
      float qv = __shfl(av.z, j);
      float w = a_self * sc;
      float wrm = w * rm;
      float4 hv = ((const float4*)(h + (size_t)m * Dd))[hl];
      s.x += w * hv.x; s.y += w * hv.y; s.z += w * hv.z; s.w += w * hv.w;
      pa.x += wrm * hv.x; pa.y += wrm * hv.y; pa.z += wrm * hv.z; pa.w += wrm * hv.w;
      qacc += w * qv;
    }
  }
  s.x += __shfl_xor(s.x, 32); s.y += __shfl_xor(s.y, 32);
  s.z += __shfl_xor(s.z, 32); s.w += __shfl_xor(s.w, 32);
  pa.x += __shfl_xor(pa.x, 32); pa.y += __shfl_xor(pa.y, 32);
  pa.z += __shfl_xor(pa.z, 32); pa.w += __shfl_xor(pa.w, 32);
  qacc += __shfl_xor(qacc, 32);
  float pd = rn * (hn4.x * wf4.x * pa.x + hn4.y * wf4.y * pa.y +
                   hn4.z * wf4.z * pa.z + hn4.w * wf4.w * pa.w);
#pragma unroll
  for (int o = 16; o; o >>= 1) pd += __shfl_xor(pd, o);
  if (lane == 0) { lq[wv] = qacc; lp[wv] = pd; }
  __syncthreads();
  if (t < 2) {
    int nn = blockIdx.x * 2 + t;
    float Qo_ = lq[t], Po_ = lp[t], Qi_ = lq[2 + t], Pi_ = lp[2 + t];
    float4 a2 = aux[nn];
    float im = (nn < Nn - 1) ? 1.0f : 0.0f;
    float so_ = luto[odix[nn]] + bo[0] - (Qo_ - 2.0f * Po_ + (2.0f - im) * a2.y);
    float si_ = luti[idix[nn]] + bi[0] - (Qi_ - 2.0f * Pi_ + (2.0f - im) * a2.z);
    float tt = expf(taup[0]) + 0.1f;
    float aa = so_ / tt, bb = si_ / tt;
    float mm = fmaxf(aa, bb);
    float ea = expf(aa - mm), eb = expf(bb - mm);
    float inv = 1.0f / (ea + eb);
    float co = ea * inv * omask[nn] + omaskb[nn];
    float ci = eb * inv * imask[nn] + imaskb[nn];
    lc[t] = co; lc[2 + t] = ci;
    if (first) { sco[nn] = co; sci[nn] = ci; }
    else       { sco[nn] += co; sci[nn] += ci; }
    if (is_pos) { co_acc[nn] += co; ci_acc[nn] += ci; }
  }
  __syncthreads();
  float c = lc[wv];
  if (lane < 32) {
    float* T = dir ? Tin : Tout;
    size_t o = (size_t)n * Dd;
    float4 v = make_float4(c * s.x, c * s.y, c * s.z, c * s.w);
    if (!first) {
      float4 old = ((const float4*)(T + o))[hl];
      v.x += old.x; v.y += old.y; v.z += old.z; v.w += old.w;
    }
    ((float4*)(T + o))[hl] = v;
  }
}

// one GEMM per conv, K=384 with register-prefetch double buffering:
// pre = (Tout/R)@Wsrc + (Tin/R)@Wdst + alpha*h@Wfc (+bias, +fused BN-stats)
__global__ __launch_bounds__(256) void k_gemmconv(
    const float* __restrict__ Tout, const float* __restrict__ Tin, const float* __restrict__ h,
    const float* __restrict__ Wsrc, const float* __restrict__ Wdst, const float* __restrict__ Wfc,
    const float* __restrict__ bsrc, const float* __restrict__ bdst, const float* __restrict__ bfc,
    const float* __restrict__ sco, const float* __restrict__ sci,
    const float* __restrict__ alphap, float* __restrict__ pre, float* __restrict__ bnsum) {
  __shared__ float Asm[64][36];
  __shared__ float Bsm[32][132];
  __shared__ float lsum[128], lsum2[128];
  int t = threadIdx.x;
  int rg = t >> 5, cg = t & 31;
  int m0 = blockIdx.x * 64;
  int arow = t >> 2, aq = t & 3;
  float alpha = alphap[0];
  float acc[8][4];
#pragma unroll
  for (int r = 0; r < 8; r++)
#pragma unroll
    for (int c = 0; c < 4; c++) acc[r][c] = 0.f;
  int bk = (t + 0) >> 5;           // B row this thread stages (pattern j): (t+j*256)>>5
  auto aptr = [&](int kt) -> const float4* {
    int sec = kt >> 2, kc = (kt & 3) * 32;
    const float* Ap = sec == 0 ? Tout : (sec == 1 ? Tin : h);
    return (const float4*)(Ap + (size_t)(m0 + arow) * Dd + kc + aq * 8);
  };
  auto bptr = [&](int kt, int j) -> const float4* {
    int sec = kt >> 2, kc = (kt & 3) * 32;
    const float* Wp = sec == 0 ? Wsrc : (sec == 1 ? Wdst : Wfc);
    int idx = t + j * 256;
    int k = idx >> 5, d4 = idx & 31;
    return (const float4*)(Wp + (size_t)(kc + k) * Dd + d4 * 4);
  };
  float4 ra0, ra1, rb[4];
  {
    const float4* ap = aptr(0);
    ra0 = ap[0]; ra1 = ap[1];
#pragma unroll
    for (int j = 0; j < 4; j++) rb[j] = *bptr(0, j);
  }
  for (int kt = 0; kt < 12; kt++) {
    float sA = (kt >= 8) ? alpha : (1.0f / (float)Rr);
    __syncthreads();
    {
      float4* d0 = (float4*)&Asm[arow][aq * 8];
      d0[0] = make_float4(ra0.x * sA, ra0.y * sA, ra0.z * sA, ra0.w * sA);
      d0[1] = make_float4(ra1.x * sA, ra1.y * sA, ra1.z * sA, ra1.w * sA);
#pragma unroll
      for (int j = 0; j < 4; j++) {
        int idx = t + j * 256;
        int k = idx >> 5, d4 = idx & 31;
        *(float4*)&Bsm[k][d4 * 4] = rb[j];
      }
    }
    // prefetch next tile into registers (completes under the FMA phase)
    float4 na0, na1, nb[4];
    if (kt < 11) {
      const float4* ap = aptr(kt + 1);
      na0 = ap[0]; na1 = ap[1];
#pragma unroll
      for (int j = 0; j < 4; j++) nb[j] = *bptr(kt + 1, j);
    }
    __syncthreads();
#pragma unroll
    for (int kk = 0; kk < 32; kk += 4) {
      float4 af[8], bf[4];
#pragma unroll
      for (int r = 0; r < 8; r++) af[r] = *(const float4*)&Asm[rg * 8 + r][kk];
#pragma unroll
      for (int j = 0; j < 4; j++) bf[j] = *(const float4*)&Bsm[kk + j][cg * 4];
#pragma unroll
      for (int r = 0; r < 8; r++) {
        const float* ap = (const float*)&af[r];
#pragma unroll
        for (int j = 0; j < 4; j++) {
          const float* bp = (const float*)&bf[j];
          acc[r][0] += ap[j] * bp[0];
          acc[r][1] += ap[j] * bp[1];
          acc[r][2] += ap[j] * bp[2];
          acc[r][3] += ap[j] * bp[3];
        }
      }
    }
    if (kt < 11) {
      ra0 = na0; ra1 = na1;
#pragma unroll
      for (int j = 0; j < 4; j++) rb[j] = nb[j];
    }
  }
  (void)bk;
  float4 vb1 = *(const float4*)(bsrc + cg * 4);
  float4 vb2 = *(const float4*)(bdst + cg * 4);
  float4 vbf = *(const float4*)(bfc + cg * 4);
  float ps[4] = {0.f, 0.f, 0.f, 0.f}, ps2[4] = {0.f, 0.f, 0.f, 0.f};
#pragma unroll
  for (int r = 0; r < 8; r++) {
    int row = m0 + rg * 8 + r;
    size_t o = (size_t)row * Dd + cg * 4;
    float s1 = sco[row] * (1.0f / (float)Rr), s2 = sci[row] * (1.0f / (float)Rr);
    float4 v;
    v.x = acc[r][0] + s1 * vb1.x + s2 * vb2.x + alpha * vbf.x;
    v.y = acc[r][1] + s1 * vb1.y + s2 * vb2.y + alpha * vbf.y;
    v.z = acc[r][2] + s1 * vb1.z + s2 * vb2.z + alpha * vbf.z;
    v.w = acc[r][3] + s1 * vb1.w + s2 * vb2.w + alpha * vbf.w;
    *(float4*)(pre + o) = v;
    ps[0] += v.x; ps[1] += v.y; ps[2] += v.z; ps[3] += v.w;
    ps2[0] += v.x * v.x; ps2[1] += v.y * v.y; ps2[2] += v.z * v.z; ps2[3] += v.w * v.w;
  }
  if (t < 128) { lsum[t] = 0.f; lsum2[t] = 0.f; }
  __syncthreads();
#pragma unroll
  for (int j = 0; j < 4; j++) {
    atomicAdd(&lsum[cg * 4 + j], ps[j]);
    atomicAdd(&lsum2[cg * 4 + j], ps2[j]);
  }
  __syncthreads();
  if (t < 128) atomicAdd(&bnsum[t], lsum[t]);
  else if (t < 256) atomicAdd(&bnsum[t], lsum2[t - 128]);
}

__global__ void k_bnapply(const float* __restrict__ pre, const float* __restrict__ sums,
                          const float* __restrict__ gamma, const float* __restrict__ beta,
                          float* __restrict__ hout, float* __restrict__ gs, int do_gs) {
  __shared__ float ls[256];
  int c = threadIdx.x & 127, sub = threadIdx.x >> 7;
  float mu = sums[c] * (1.0f / (float)Nn);
  float var = sums[c + 128] * (1.0f / (float)Nn) - mu * mu;
  float sc = gamma[c] / sqrtf(var + BN_EPS);
  float bt = beta[c];
  float g = 0.f;
  for (int n = blockIdx.x * 2 + sub; n < Nn; n += gridDim.x * 2) {
    float v = (pre[(size_t)n * Dd + c] - mu) * sc + bt;
    v = fmaxf(v, 0.f);
    hout[(size_t)n * Dd + c] = v;
    g += v;
  }
  if (do_gs) {
    ls[threadIdx.x] = g;
    __syncthreads();
    if (sub == 0) atomicAdd(&gs[c], (ls[c] + ls[c + 128]) * (1.0f / (float)Nn));
  }
}

// logp + folded c_in/c_out outputs (one block per node)
__global__ __launch_bounds__(64) void k_logp(const float* __restrict__ ph0, const float* __restrict__ ph1,
                      const float* __restrict__ Wlin, const float* __restrict__ blin,
                      const float* __restrict__ ci_acc, const float* __restrict__ co_acc,
                      float* __restrict__ cins, float* __restrict__ couts,
                      float* __restrict__ logp) {
  __shared__ float jk[Dd];
  __shared__ float lg[Cc];
  int n = blockIdx.x, t = threadIdx.x;
  if (t == 63) {
    cins[n] = ci_acc[n] * (1.0f / (float)(Ll * Rr));
    couts[n] = co_acc[n] * (1.0f / (float)(Ll * Rr));
  }
  for (int d = t; d < Dd; d += 64) jk[d] = fmaxf(ph0[(size_t)n * Dd + d], ph1[(size_t)n * Dd + d]);
  __syncthreads();
  if (t < Cc) {
    float acc = blin[t];
    for (int k = 0; k < Dd; k++) acc += jk[k] * Wlin[k * Cc + t];
    lg[t] = acc;
  }
  __syncthreads();
  float m = -1e30f;
  for (int c = 0; c < Cc; c++) m = fmaxf(m, lg[c]);
  float s = 0.f;
  for (int c = 0; c < Cc; c++) s += expf(lg[c] - m);
  float lse = m + logf(s);
  if (t < Cc) logp[(size_t)n * Cc + t] = lg[t] - lse;
}

// ---------------- host ----------------
extern "C" void kernel_launch(void* const* d_in, const int* in_sizes, int n_in,
                              void* d_out, int out_size, void* d_ws, size_t ws_size,
                              hipStream_t stream) {
  const float* x      = (const float*)d_in[0];
  const int*   ei     = (const int*)d_in[1];
  const float* W_src  = (const float*)d_in[2];
  const float* b_src  = (const float*)d_in[3];
  const float* W_dst  = (const float*)d_in[4];
  const float* b_dst  = (const float*)d_in[5];
  const float* W_outf = (const float*)d_in[6];
  const float* b_outf = (const float*)d_in[7];
  const float* W_inf  = (const float*)d_in[8];
  const float* b_inf  = (const float*)d_in[9];
  const float* W_fc   = (const float*)d_in[10];
  const float* b_fc   = (const float*)d_in[11];
  const float* gamma  = (const float*)d_in[12];
  const float* beta   = (const float*)d_in[13];
  const float* oemb   = (const float*)d_in[14];
  const float* iemb   = (const float*)d_in[15];
  const float* omask  = (const float*)d_in[16];
  const float* omaskb = (const float*)d_in[17];
  const float* imask  = (const float*)d_in[18];
  const float* imaskb = (const float*)d_in[19];
  const float* alphap = (const float*)d_in[20];
  const float* taup   = (const float*)d_in[21];
  const float* Wlin   = (const float*)d_in[22];
  const float* blin   = (const float*)d_in[23];

  float* out   = (float*)d_out;
  float* logp  = out;
  float* cins  = logp + (size_t)Nn * Cc;
  float* couts = cins + Nn;
  float* ph0   = couts + Nn;
  float* ph1   = ph0 + (size_t)Nn * Dd;
  float* nh0   = ph1 + (size_t)Nn * Dd;
  float* nh1   = nh0 + (size_t)Nn * Dd;
  float* gs0   = nh1 + (size_t)Nn * Dd;
  float* gs1   = gs0 + Dd;

  char* p = (char*)d_ws;
  auto alloc = [&](size_t bytes) -> void* {
    void* q = (void*)p;
    p += (bytes + 255) & ~(size_t)255;
    return q;
  };
  float* pre   = (float*)alloc((size_t)Nn * Dd * 4);
  float* Tout  = (float*)alloc((size_t)Nn * Dd * 4);
  float* Tin   = (float*)alloc((size_t)Nn * Dd * 4);
  float* hperm = (float*)alloc((size_t)Nn * Dd * 4);
  unsigned* pbuf = (unsigned*)alloc((size_t)6 * Ee * 4);
  size_t qwords = (size_t)6 * Ee;
  size_t pwords = (size_t)(6 * 3 * HR_SB) * HR_PAD;
  unsigned* qbuf = (unsigned*)alloc((qwords > pwords ? qwords : pwords) * 4);
  int* partials = (int*)qbuf;
  int* csr_off = (int*)alloc((size_t)Rr * (Nn + 1) * 4);
  int* csc_off = (int*)alloc((size_t)Rr * (Nn + 1) * 4);
  int* odeg    = (int*)alloc((size_t)Rr * Nn * 4);
  int* ideg    = (int*)alloc((size_t)Rr * Nn * 4);
  float* ods   = (float*)alloc((size_t)Rr * Nn * 4);
  float* ids   = (float*)alloc((size_t)Rr * Nn * 4);
  int* odix    = (int*)alloc((size_t)Rr * Nn * 4);
  int* idix    = (int*)alloc((size_t)Rr * Nn * 4);
  float4* aux  = (float4*)alloc((size_t)Nn * 16);
  float4* auxrd = (float4*)alloc((size_t)6 * Nn * 16);
  float* sco   = (float*)alloc((size_t)Nn * 4 * 2);
  float* sci   = sco + Nn;
  float* coacc = (float*)alloc((size_t)Nn * 4 * 2);
  float* ciacc = coacc + Nn;
  float* luto  = (float*)alloc((size_t)2 * MAXD * 4);
  float* luti  = (float*)alloc((size_t)2 * MAXD * 4);
  float* bnsum = (float*)alloc(256 * 4);
  unsigned* kbuf0 = (unsigned*)alloc((size_t)2 * Nn * 4);
  unsigned* kbuf1 = (unsigned*)alloc((size_t)2 * Nn * 4);
  int* vbuf0 = (int*)alloc((size_t)2 * Nn * 4);
  int* vbuf1 = (int*)alloc((size_t)2 * Nn * 4);
  int* rhist = (int*)alloc((size_t)2 * (RB_H + 1) * 4);
  int* rscan = (int*)alloc((size_t)2 * (RB_H + 1) * 4);
  int* ehist = (int*)alloc((size_t)6 * EB_H * 4);
  int* escan = (int*)alloc((size_t)6 * (EB_H + 1) * 4);

  // ---- graph structure ----
  k_hist2<<<6 * 3 * HR_SB, 256, 0, stream>>>(ei, partials);
  k_hreduce<<<(6 * Nn + 255) / 256, 256, 0, stream>>>(partials, odeg, ideg);
  k_degnorm<<<(Rr * Nn + 255) / 256, 256, 0, stream>>>(odeg, ideg, ods, ids, odix, idix);
  k_scan6<<<6, 1024, 0, stream>>>(odeg, ideg, csr_off, csc_off);
  k_pack<<<(3 * Ee + 255) / 256, 256, 0, stream>>>(ei, pbuf, pbuf + (size_t)3 * Ee);
  k_ehist<<<6 * EB_NB, 256, 0, stream>>>(pbuf, ehist, 16);
  k_escan6<<<6, 1024, 0, stream>>>(ehist, escan);
  k_escatter<<<6 * EB_NB, 256, 0, stream>>>(pbuf, escan, 16, qbuf);
  k_ehist<<<6 * EB_NB, 256, 0, stream>>>(qbuf, ehist, 24);
  k_escan6<<<6, 1024, 0, stream>>>(ehist, escan);
  k_escatter<<<6 * EB_NB, 256, 0, stream>>>(qbuf, escan, 24, pbuf);
  hipMemsetAsync(coacc, 0, (size_t)Nn * 4 * 2, stream);
  k_lut2<<<2 * MAXD / 4, 256, 0, stream>>>(oemb, iemb, W_outf, W_inf, luto, luti);

  // ---- both permutations, batched (seeds 100 & 101) ----
  auto radix4b = [&]() {
    for (int pass = 0; pass < 4; pass++) {
      const unsigned* ik = (pass & 1) ? kbuf1 : kbuf0;
      const int*      iv = (pass & 1) ? vbuf1 : vbuf0;
      unsigned*       ok = (pass & 1) ? kbuf0 : kbuf1;
      int*            ov = (pass & 1) ? vbuf0 : vbuf1;
      int shift = pass * 8;
      k_rhist2<<<2 * RB_NB, 256, 0, stream>>>(ik, rhist, shift);
      k_scanP<<<2, 1024, 0, stream>>>(rhist, rscan);
      k_rscatter2<<<2 * RB_NB, 256, 0, stream>>>(ik, iv, rscan, shift, ok, ov);
    }
  };
  k_genkeys2<<<(2 * Nn + 255) / 256, 256, 0, stream>>>(kbuf0, 100u, 101u, 1, vbuf0, 1);
  radix4b();
  k_genkeys2<<<(2 * Nn + 255) / 256, 256, 0, stream>>>(kbuf0, 100u, 101u, 2, vbuf0, 0);
  radix4b();

  auto conv = [&](int l, const float* hin, float* hout, float* gs, int is_pos) {
    const float* Wfo = W_outf + l * Dd;
    const float* Wfi = W_inf + l * Dd;
    k_rowscalar<<<Nn / 4, 256, 0, stream>>>(hin, Wfo, Wfi, aux, ods, ids, auxrd, bnsum,
                                            is_pos ? gs : nullptr);
    for (int r = 0; r < Rr; r++) {
      k_csrdir3<<<Nn / 2, 256, 0, stream>>>(csr_off + r * (Nn + 1), pbuf + (size_t)r * Ee,
                                            csc_off + r * (Nn + 1), pbuf + (size_t)(3 + r) * Ee,
                                            ods + r * Nn, ids + r * Nn,
                                            auxrd + (size_t)(2 * r) * Nn,
                                            auxrd + (size_t)(2 * r + 1) * Nn,
                                            aux, hin, Wfo, Wfi,
                                            luto + l * MAXD, luti + l * MAXD,
                                            odix + r * Nn, idix + r * Nn,
                                            b_outf + l, b_inf + l, taup,
                                            omask + (size_t)r * Nn, omaskb + (size_t)r * Nn,
                                            imask + (size_t)r * Nn, imaskb + (size_t)r * Nn,
                                            Tout, Tin, sco, sci, coacc, ciacc,
                                            r == 0 ? 1 : 0, is_pos);
    }
    k_gemmconv<<<Nn / 64, 256, 0, stream>>>(Tout, Tin, hin,
                                            W_src + (size_t)l * Dd * Dd, W_dst + (size_t)l * Dd * Dd,
                                            W_fc + (size_t)l * Dd * Dd,
                                            b_src + l * Dd, b_dst + l * Dd, b_fc + l * Dd,
                                            sco, sci, alphap, pre, bnsum);
    k_bnapply<<<256, 256, 0, stream>>>(pre, bnsum, gamma + l * Dd, beta + l * Dd, hout, gs, is_pos);
  };

  // ---- layer 0 ----
  conv(0, x, ph0, gs0, 1);
  k_permrows<<<Nn / 8, 256, 0, stream>>>(x, vbuf0, hperm);
  conv(0, hperm, nh0, nullptr, 0);

  // ---- layer 1 ----
  conv(1, ph0, ph1, gs1, 1);
  k_permrows<<<Nn / 8, 256, 0, stream>>>(nh0, vbuf0 + Nn, hperm);
  conv(1, hperm, nh1, nullptr, 0);

  // ---- outputs ----
  k_logp<<<Nn, 64, 0, stream>>>(ph0, ph1, Wlin, blin, ciacc, coacc, cins, couts, logp);
}

// Round 13
// 2277.376 us; speedup vs baseline: 1.1995x; 1.1995x over previous
//
#include <hip/hip_runtime.h>

// ---------------- problem constants ----------------
constexpr int Nn = 40000;
constexpr int Dd = 128;
constexpr int Rr = 3;
constexpr int Ee = 640000;
constexpr int Ll = 2;
constexpr int Cc = 40;
constexpr int MAXD = 512;
constexpr float BN_EPS = 1e-5f;

// radix sort geometry (permutation keys, 2 batched segments)
constexpr int RB_ELEMS = 1024;
constexpr int RB_NB = (Nn + RB_ELEMS - 1) / RB_ELEMS; // 40 blocks per segment
constexpr int RB_BINS = 256;
constexpr int RB_H = RB_BINS * RB_NB;                 // hist entries per segment

// edge sort geometry
constexpr int EB_ELEMS = 4096;
constexpr int EB_NB = (Ee + EB_ELEMS - 1) / EB_ELEMS; // 157
constexpr int EB_H = 256 * EB_NB;                     // hist entries per array

// histogram geometry
constexpr int HR_BINS = 13334;  // ceil(Nn/3)
constexpr int HR_PAD = 13344;
constexpr int HR_SB = 16;
constexpr int HR_CHUNK = (Ee + HR_SB - 1) / HR_SB;

// ---------------- threefry-2x32 (JAX-compatible) ----------------
__device__ __forceinline__ unsigned rotl32(unsigned x, int d) { return (x << d) | (x >> (32 - d)); }

__device__ void threefry2x32(unsigned k0, unsigned k1, unsigned c0, unsigned c1,
                             unsigned& o0, unsigned& o1) {
  unsigned ks2 = k0 ^ k1 ^ 0x1BD11BDAu;
  unsigned x0 = c0 + k0, x1 = c1 + k1;
#define TFR4(a,b,c,d2) \
  x0 += x1; x1 = rotl32(x1,a);  x1 ^= x0; \
  x0 += x1; x1 = rotl32(x1,b);  x1 ^= x0; \
  x0 += x1; x1 = rotl32(x1,c);  x1 ^= x0; \
  x0 += x1; x1 = rotl32(x1,d2); x1 ^= x0;
  TFR4(13,15,26,6);  x0 += k1;  x1 += ks2 + 1u;
  TFR4(17,29,16,24); x0 += ks2; x1 += k0 + 2u;
  TFR4(13,15,26,6);  x0 += k0;  x1 += k1 + 3u;
  TFR4(17,29,16,24); x0 += k1;  x1 += ks2 + 4u;
  TFR4(13,15,26,6);  x0 += ks2; x1 += k0 + 5u;
#undef TFR4
  o0 = x0; o1 = x1;
}

// batched over 2 segments (seeds seed0, seed1); local index per segment
__global__ void k_genkeys2(unsigned* __restrict__ keys, unsigned seed0, unsigned seed1,
                           int rounds, int* __restrict__ vout, int doIota) {
  int i = blockIdx.x * blockDim.x + threadIdx.x;
  if (i >= 2 * Nn) return;
  int seg = i / Nn, li = i - seg * Nn;
  unsigned seed = seg ? seed1 : seed0;
  unsigned k0 = 0u, k1 = seed, sk0 = 0u, sk1 = 0u;
  for (int rd = 0; rd < rounds; rd++) {
    unsigned a0, a1, b0, b1;
    threefry2x32(k0, k1, 0u, 0u, a0, a1);
    threefry2x32(k0, k1, 0u, 1u, b0, b1);
    sk0 = b0; sk1 = b1;
    k0 = a0; k1 = a1;
  }
  unsigned o0, o1;
  threefry2x32(sk0, sk1, 0u, (unsigned)li, o0, o1);
  keys[i] = o0 ^ o1;
  if (doIota) vout[i] = li;
}

// ---------------- LSD radix sort for permutations (stable, 2 segments) ----------------
__global__ void k_rhist2(const unsigned* __restrict__ keys, int* __restrict__ hist, int shift) {
  __shared__ int lh[RB_BINS];
  int a = blockIdx.x / RB_NB, blk = blockIdx.x % RB_NB;
  const unsigned* src = keys + (size_t)a * Nn;
  int t = threadIdx.x;
  lh[t] = 0;
  __syncthreads();
  int base = blk * RB_ELEMS;
  for (int i = t; i < RB_ELEMS; i += 256) {
    int g = base + i;
    if (g < Nn) atomicAdd(&lh[(src[g] >> shift) & 255], 1);
  }
  __syncthreads();
  hist[(size_t)a * RB_H + t * RB_NB + blk] = lh[t];
}

__device__ void scan_body(const int* cnt, int* off, int n, int items) {
  int t = threadIdx.x;
  int lo = t * items, hi = min(lo + items, n);
  int s = 0;
  for (int i = lo; i < hi; i++) s += cnt[i];
  int lane = t & 63, wid = t >> 6;
  int sc = s;
#pragma unroll
  for (int o = 1; o < 64; o <<= 1) {
    int v = __shfl_up(sc, o);
    if (lane >= o) sc += v;
  }
  __shared__ int wsum[16], woff[16];
  if (lane == 63) wsum[wid] = sc;
  __syncthreads();
  if (t == 0) {
    int a = 0;
    for (int w = 0; w < 16; w++) { woff[w] = a; a += wsum[w]; }
    off[n] = a;
  }
  __syncthreads();
  int run = woff[wid] + sc - s;
  for (int i = lo; i < hi; i++) {
    int v = cnt[i];
    off[i] = run;
    run += v;
  }
}

// 2-segment scan for the perm-sort histograms
__global__ __launch_bounds__(1024) void k_scanP(const int* __restrict__ hist, int* __restrict__ esc) {
  int a = blockIdx.x;
  scan_body(hist + (size_t)a * RB_H, esc + (size_t)a * (RB_H + 1), RB_H, (RB_H + 1023) / 1024);
}

// 6 independent scans (3 csr + 3 csc) in one dispatch
__global__ __launch_bounds__(1024) void k_scan6(const int* __restrict__ odeg, const int* __restrict__ ideg,
                                                int* __restrict__ csr_off, int* __restrict__ csc_off) {
  int b = blockIdx.x;
  const int* cnt = (b < 3) ? (odeg + b * Nn) : (ideg + (b - 3) * Nn);
  int* off = (b < 3) ? (csr_off + b * (Nn + 1)) : (csc_off + (b - 3) * (Nn + 1));
  scan_body(cnt, off, Nn, (Nn + 1023) / 1024);
}

__global__ void k_rscatter2(const unsigned* __restrict__ keys, const int* __restrict__ vals,
                            const int* __restrict__ scanned, int shift,
                            unsigned* __restrict__ okeys, int* __restrict__ ovals) {
  __shared__ int running[RB_BINS];
  __shared__ int wcount[4][RB_BINS];
  __shared__ int dbase[RB_BINS];
  int a = blockIdx.x / RB_NB, blk = blockIdx.x % RB_NB;
  const unsigned* ksrc = keys + (size_t)a * Nn;
  const int* vsrc = vals + (size_t)a * Nn;
  unsigned* kdst = okeys + (size_t)a * Nn;
  int* vdst = ovals + (size_t)a * Nn;
  int t = threadIdx.x;
  int lane = t & 63, w = t >> 6;
  running[t] = 0;
  dbase[t] = scanned[(size_t)a * (RB_H + 1) + t * RB_NB + blk];
  int base = blk * RB_ELEMS;
  for (int rnd = 0; rnd < 4; rnd++) {
#pragma unroll
    for (int q = 0; q < 4; q++) wcount[q][t] = 0;
    __syncthreads();
    int g = base + rnd * 256 + t;
    bool valid = g < Nn;
    unsigned key = valid ? ksrc[g] : 0u;
    int d = (key >> shift) & 255;
    unsigned long long bb = __ballot(valid);
    unsigned long long mask = bb;
#pragma unroll
    for (int k = 0; k < 8; k++) {
      bool b = (d >> k) & 1;
      unsigned long long tt = __ballot(b && valid);
      mask &= b ? tt : ~tt;
    }
    mask &= bb;
    int riw = __popcll(mask & ((1ull << lane) - 1ull));
    int cnt_ = __popcll(mask);
    if (valid && riw == 0) wcount[w][d] = cnt_;
    __syncthreads();
    if (valid) {
      int prior = 0;
#pragma unroll
      for (int ww = 0; ww < 4; ww++) if (ww < w) prior += wcount[ww][d];
      int gp = dbase[d] + running[d] + prior + riw;
      kdst[gp] = key;
      vdst[gp] = vsrc[g];
    }
    __syncthreads();
    running[t] += wcount[0][t] + wcount[1][t] + wcount[2][t] + wcount[3][t];
    __syncthreads();
  }
}

__global__ void k_permrows(const float* __restrict__ src, const int* __restrict__ perm,
                           float* __restrict__ dst) {
  int row = blockIdx.x * 8 + (threadIdx.x >> 5);
  int lane = threadIdx.x & 31;
  if (row >= Nn) return;
  int p = perm[row];
  ((float4*)(dst + (size_t)row * Dd))[lane] = ((const float4*)(src + (size_t)p * Dd))[lane];
}

// ---------------- graph structure (atomic-free histogram) ----------------
__global__ __launch_bounds__(256) void k_hist2(const int* __restrict__ ei, int* __restrict__ partials) {
  __shared__ int lh[HR_BINS];
  int bid = blockIdx.x;  // j*(3*HR_SB) + range*HR_SB + sb
  int sb = bid % HR_SB;
  int range = (bid / HR_SB) % 3;
  int j = bid / (3 * HR_SB);
  int rel = j >> 1, which = j & 1;
  const int* src = ei + (size_t)rel * 2 * Ee + (size_t)which * Ee;
  int lo = range * HR_BINS;
  for (int i = threadIdx.x; i < HR_BINS; i += 256) lh[i] = 0;
  __syncthreads();
  int e0 = sb * HR_CHUNK, e1 = min(e0 + HR_CHUNK, Ee);
  for (int e = e0 + threadIdx.x; e < e1; e += 256) {
    int v = src[e] - lo;
    if (v >= 0 && v < HR_BINS) atomicAdd(&lh[v], 1);
  }
  __syncthreads();
  int* dst = partials + (size_t)bid * HR_PAD;
  for (int i = threadIdx.x; i < HR_BINS; i += 256) dst[i] = lh[i];
}

__global__ void k_hreduce(const int* __restrict__ partials, int* __restrict__ odeg,
                          int* __restrict__ ideg) {
  int idx = blockIdx.x * 256 + threadIdx.x;
  if (idx >= 6 * Nn) return;
  int j = idx / Nn, bin = idx - j * Nn;
  int range = bin / HR_BINS, off = bin - range * HR_BINS;
  const int* p = partials + (size_t)((j * 3 + range) * HR_SB) * HR_PAD + off;
  int sum = 0;
#pragma unroll
  for (int b = 0; b < HR_SB; b++) sum += p[(size_t)b * HR_PAD];
  int rel = j >> 1;
  (j & 1 ? ideg : odeg)[rel * Nn + bin] = sum;
}

__global__ void k_degnorm(const int* __restrict__ odeg, const int* __restrict__ ideg,
                          float* __restrict__ ods, float* __restrict__ ids,
                          int* __restrict__ odix, int* __restrict__ idix) {
  int idx = blockIdx.x * blockDim.x + threadIdx.x;
  if (idx >= Rr * Nn) return;
  int od = odeg[idx], id_ = ideg[idx];
  ods[idx] = od > 0 ? 1.0f / sqrtf((float)od) : 0.0f;
  ids[idx] = id_ > 0 ? 1.0f / sqrtf((float)id_) : 0.0f;
  odix[idx] = od < MAXD - 1 ? od : MAXD - 1;
  idix[idx] = id_ < MAXD - 1 ? id_ : MAXD - 1;
}

// pack edges: pcsr[rel][e] = (row<<16)|col ; pcsc[rel][e] = (col<<16)|row
__global__ void k_pack(const int* __restrict__ ei, unsigned* __restrict__ pcsr,
                       unsigned* __restrict__ pcsc) {
  int idx = blockIdx.x * 256 + threadIdx.x;
  if (idx >= 3 * Ee) return;
  int r = idx / Ee, e = idx - r * Ee;
  const int* base = ei + (size_t)r * 2 * Ee;
  unsigned rw = (unsigned)base[e], cl = (unsigned)base[Ee + e];
  pcsr[idx] = (rw << 16) | cl;
  pcsc[idx] = (cl << 16) | rw;
}

// edge radix: histogram per (array, block)
__global__ __launch_bounds__(256) void k_ehist(const unsigned* __restrict__ pin,
                                               int* __restrict__ hist, int shift) {
  __shared__ int lh[256];
  int a = blockIdx.x / EB_NB, blk = blockIdx.x % EB_NB;
  const unsigned* src = pin + (size_t)a * Ee;
  lh[threadIdx.x] = 0;
  __syncthreads();
  int base = blk * EB_ELEMS;
  for (int i = threadIdx.x; i < EB_ELEMS; i += 256) {
    int g = base + i;
    if (g < Ee) atomicAdd(&lh[(src[g] >> shift) & 255], 1);
  }
  __syncthreads();
  hist[(size_t)a * EB_H + threadIdx.x * EB_NB + blk] = lh[threadIdx.x];
}

// 6 scans of EB_H entries each
__global__ __launch_bounds__(1024) void k_escan6(const int* __restrict__ hist, int* __restrict__ esc) {
  int a = blockIdx.x;
  scan_body(hist + (size_t)a * EB_H, esc + (size_t)a * (EB_H + 1), EB_H, (EB_H + 1023) / 1024);
}

// stable scatter of packed edges (16 rounds of 256)
__global__ __launch_bounds__(256) void k_escatter(const unsigned* __restrict__ pin,
                                                  const int* __restrict__ esc, int shift,
                                                  unsigned* __restrict__ pout) {
  __shared__ int running[256];
  __shared__ int wcount[4][256];
  __shared__ int dbase[256];
  int a = blockIdx.x / EB_NB, blk = blockIdx.x % EB_NB;
  const unsigned* src = pin + (size_t)a * Ee;
  unsigned* dst = pout + (size_t)a * Ee;
  int t = threadIdx.x;
  int lane = t & 63, w = t >> 6;
  running[t] = 0;
  dbase[t] = esc[(size_t)a * (EB_H + 1) + t * EB_NB + blk];
  int base = blk * EB_ELEMS;
  for (int rnd = 0; rnd < 16; rnd++) {
#pragma unroll
    for (int q = 0; q < 4; q++) wcount[q][t] = 0;
    __syncthreads();
    int g = base + rnd * 256 + t;
    bool valid = g < Ee;
    unsigned key = valid ? src[g] : 0u;
    int d = (key >> shift) & 255;
    unsigned long long bb = __ballot(valid);
    unsigned long long mask = bb;
#pragma unroll
    for (int k = 0; k < 8; k++) {
      bool b = (d >> k) & 1;
      unsigned long long tt = __ballot(b && valid);
      mask &= b ? tt : ~tt;
    }
    mask &= bb;
    int riw = __popcll(mask & ((1ull << lane) - 1ull));
    int cnt_ = __popcll(mask);
    if (valid && riw == 0) wcount[w][d] = cnt_;
    __syncthreads();
    if (valid) {
      int prior = 0;
#pragma unroll
      for (int ww = 0; ww < 4; ww++) if (ww < w) prior += wcount[ww][d];
      int gp = dbase[d] + running[d] + prior + riw;
      dst[gp] = key;
    }
    __syncthreads();
    running[t] += wcount[0][t] + wcount[1][t] + wcount[2][t] + wcount[3][t];
    __syncthreads();
  }
}

// ---------------- per-conv kernels ----------------
// aux[n] = (rinv, qo, qi, 0); auxrd[(2r+dir)][n] = (nbr-scale, rinv, q);
// block 0 also zeroes bnsum (and gs for pos convs).
__global__ void k_rowscalar(const float* __restrict__ h, const float* __restrict__ Wfo,
                            const float* __restrict__ Wfi, float4* __restrict__ aux,
                            const float* __restrict__ ods, const float* __restrict__ ids,
                            float4* __restrict__ auxrd,
                            float* __restrict__ bnsum, float* __restrict__ gs) {
  if (blockIdx.x == 0) {
    bnsum[threadIdx.x] = 0.f;
    if (gs != nullptr && threadIdx.x < Dd) gs[threadIdx.x] = 0.f;
  }
  int wid = (blockIdx.x * blockDim.x + threadIdx.x) >> 6;
  int lane = threadIdx.x & 63;
  if (wid >= Nn) return;
  float2 a = ((const float2*)(h + (size_t)wid * Dd))[lane];
  float2 wo = ((const float2*)Wfo)[lane];
  float2 wi = ((const float2*)Wfi)[lane];
  float l1 = fabsf(a.x) + fabsf(a.y);
  float so = a.x * a.x * wo.x + a.y * a.y * wo.y;
  float si = a.x * a.x * wi.x + a.y * a.y * wi.y;
#pragma unroll
  for (int o = 32; o; o >>= 1) {
    l1 += __shfl_xor(l1, o);
    so += __shfl_xor(so, o);
    si += __shfl_xor(si, o);
  }
  if (lane == 0) {
    float ri = 1.0f / (l1 + 1e-12f);
    float qo = ri * ri * so, qi = ri * ri * si;
    aux[wid] = make_float4(ri, qo, qi, 0.f);
#pragma unroll
    for (int r = 0; r < Rr; r++) {
      auxrd[(size_t)(2 * r) * Nn + wid] = make_float4(ids[r * Nn + wid], ri, qo, 0.f);
      auxrd[(size_t)(2 * r + 1) * Nn + wid] = make_float4(ods[r * Nn + wid], ri, qi, 0.f);
    }
  }
}

// both layers' LUTs in one dispatch: luto/luti are [2][MAXD]
__global__ void k_lut2(const float* __restrict__ eo, const float* __restrict__ ei_,
                       const float* __restrict__ W_outf, const float* __restrict__ W_inf,
                       float* __restrict__ luto, float* __restrict__ luti) {
  int wid = (blockIdx.x * blockDim.x + threadIdx.x) >> 6;
  int lane = threadIdx.x & 63;
  if (wid >= 2 * MAXD) return;
  int l = wid >> 9, k = wid & (MAXD - 1);
  float2 a = ((const float2*)(eo + ((size_t)l * MAXD + k) * Dd))[lane];
  float2 b = ((const float2*)(ei_ + ((size_t)l * MAXD + k) * Dd))[lane];
  float2 wo = ((const float2*)(W_outf + l * Dd))[lane];
  float2 wi = ((const float2*)(W_inf + l * Dd))[lane];
  float so = a.x * wo.x + a.y * wo.y;
  float si = b.x * wi.x + b.y * wi.y;
#pragma unroll
  for (int o = 32; o; o >>= 1) { so += __shfl_xor(so, o); si += __shfl_xor(si, o); }
  if (lane == 0) { luto[wid] = so; luti[wid] = si; }
}

// fused gather + score + T accumulation. 256 threads = 4 waves = 2 nodes x 2 dirs.
// PROVEN 2-edge inner loop; per-edge operands packed in one float4 gather.
__global__ __launch_bounds__(256) void k_csrdir3(
    const int* __restrict__ csr_off, const unsigned* __restrict__ pcsr,
    const int* __restrict__ csc_off, const unsigned* __restrict__ pcsc,
    const float* __restrict__ ods_r, const float* __restrict__ ids_r,
    const float4* __restrict__ auxo, const float4* __restrict__ auxi,
    const float4* __restrict__ aux, const float* __restrict__ h,
    const float* __restrict__ Wfo, const float* __restrict__ Wfi,
    const float* __restrict__ luto, const float* __restrict__ luti,
    const int* __restrict__ odix, const int* __restrict__ idix,
    const float* __restrict__ bo, const float* __restrict__ bi,
    const float* __restrict__ taup,
    const float* __restrict__ omask, const float* __restrict__ omaskb,
    const float* __restrict__ imask, const float* __restrict__ imaskb,
    float* __restrict__ Tout, float* __restrict__ Tin,
    float* __restrict__ sco, float* __restrict__ sci,
    float* __restrict__ co_acc, float* __restrict__ ci_acc,
    int first, int is_pos) {
  __shared__ float lq[4], lp[4], lc[4];
  int t = threadIdx.x;
  int wv = t >> 6, lane = t & 63;
  int dir = wv >> 1;
  int n = blockIdx.x * 2 + (wv & 1);
  const int* off = dir ? csc_off : csr_off;
  const unsigned* nbrp = dir ? pcsc : pcsr;
  const float4* auxd = dir ? auxi : auxo;
  float a_self = (dir ? ids_r : ods_r)[n];
  const float* Wf = dir ? Wfi : Wfo;
  int s0 = off[n], s1 = off[n + 1];
  int hl = lane & 31, half = lane >> 5;
  float4 wf4 = ((const float4*)Wf)[hl];
  float4 hn4 = ((const float4*)(h + (size_t)n * Dd))[hl];
  float rn = aux[n].x;
  float4 s = make_float4(0.f, 0.f, 0.f, 0.f);
  float4 pa = make_float4(0.f, 0.f, 0.f, 0.f);
  float qacc = 0.f;
  for (int base = s0; base < s1; base += 64) {
    int eidx = base + lane;
    bool valid = eidx < s1;
    int mi = valid ? (int)(nbrp[eidx] & 0xFFFFu) : 0;
    float4 av = valid ? auxd[mi] : make_float4(0.f, 0.f, 0.f, 0.f);
    int cnt = min(64, s1 - base);
#pragma unroll 4
    for (int j = half; j < cnt; j += 2) {
      int m = __shfl(mi, j);
      float sc = __shfl(av.x, j);
      float rm = __shfl(av.y, j);
      float qv = __shfl(av.z, j);
      float w = a_self * sc;
      float wrm = w * rm;
      float4 hv = ((const float4*)(h + (size_t)m * Dd))[hl];
      s.x += w * hv.x; s.y += w * hv.y; s.z += w * hv.z; s.w += w * hv.w;
      pa.x += wrm * hv.x; pa.y += wrm * hv.y; pa.z += wrm * hv.z; pa.w += wrm * hv.w;
      qacc += w * qv;
    }
  }
  s.x += __shfl_xor(s.x, 32); s.y += __shfl_xor(s.y, 32);
  s.z += __shfl_xor(s.z, 32); s.w += __shfl_xor(s.w, 32);
  pa.x += __shfl_xor(pa.x, 32); pa.y += __shfl_xor(pa.y, 32);
  pa.z += __shfl_xor(pa.z, 32); pa.w += __shfl_xor(pa.w, 32);
  qacc += __shfl_xor(qacc, 32);
  float pd = rn * (hn4.x * wf4.x * pa.x + hn4.y * wf4.y * pa.y +
                   hn4.z * wf4.z * pa.z + hn4.w * wf4.w * pa.w);
#pragma unroll
  for (int o = 16; o; o >>= 1) pd += __shfl_xor(pd, o);
  if (lane == 0) { lq[wv] = qacc; lp[wv] = pd; }
  __syncthreads();
  if (t < 2) {
    int nn = blockIdx.x * 2 + t;
    float Qo_ = lq[t], Po_ = lp[t], Qi_ = lq[2 + t], Pi_ = lp[2 + t];
    float4 a2 = aux[nn];
    float im = (nn < Nn - 1) ? 1.0f : 0.0f;
    float so_ = luto[odix[nn]] + bo[0] - (Qo_ - 2.0f * Po_ + (2.0f - im) * a2.y);
    float si_ = luti[idix[nn]] + bi[0] - (Qi_ - 2.0f * Pi_ + (2.0f - im) * a2.z);
    float tt = expf(taup[0]) + 0.1f;
    float aa = so_ / tt, bb = si_ / tt;
    float mm = fmaxf(aa, bb);
    float ea = expf(aa - mm), eb = expf(bb - mm);
    float inv = 1.0f / (ea + eb);
    float co = ea * inv * omask[nn] + omaskb[nn];
    float ci = eb * inv * imask[nn] + imaskb[nn];
    lc[t] = co; lc[2 + t] = ci;
    if (first) { sco[nn] = co; sci[nn] = ci; }
    else       { sco[nn] += co; sci[nn] += ci; }
    if (is_pos) { co_acc[nn] += co; ci_acc[nn] += ci; }
  }
  __syncthreads();
  float c = lc[wv];
  if (lane < 32) {
    float* T = dir ? Tin : Tout;
    size_t o = (size_t)n * Dd;
    float4 v = make_float4(c * s.x, c * s.y, c * s.z, c * s.w);
    if (!first) {
      float4 old = ((const float4*)(T + o))[hl];
      v.x += old.x; v.y += old.y; v.z += old.z; v.w += old.w;
    }
    ((float4*)(T + o))[hl] = v;
  }
}

// one GEMM per conv, K=384 (simple proven R10 body):
// pre = (Tout/R)@Wsrc + (Tin/R)@Wdst + alpha*h@Wfc (+bias, +fused BN-stats)
__global__ __launch_bounds__(256) void k_gemmconv(
    const float* __restrict__ Tout, const float* __restrict__ Tin, const float* __restrict__ h,
    const float* __restrict__ Wsrc, const float* __restrict__ Wdst, const float* __restrict__ Wfc,
    const float* __restrict__ bsrc, const float* __restrict__ bdst, const float* __restrict__ bfc,
    const float* __restrict__ sco, const float* __restrict__ sci,
    const float* __restrict__ alphap, float* __restrict__ pre, float* __restrict__ bnsum) {
  __shared__ float Asm[64][36];
  __shared__ float Bsm[32][132];
  __shared__ float lsum[128], lsum2[128];
  int t = threadIdx.x;
  int rg = t >> 5, cg = t & 31;
  int m0 = blockIdx.x * 64;
  int arow = t >> 2, aq = t & 3;
  float alpha = alphap[0];
  float acc[8][4];
#pragma unroll
  for (int r = 0; r < 8; r++)
#pragma unroll
    for (int c = 0; c < 4; c++) acc[r][c] = 0.f;
  for (int kt = 0; kt < 12; kt++) {
    int sec = kt >> 2, kc = (kt & 3) * 32;
    const float* Ap = sec == 0 ? Tout : (sec == 1 ? Tin : h);
    const float* Wp = sec == 0 ? Wsrc : (sec == 1 ? Wdst : Wfc);
    float sA = (sec == 2) ? alpha : (1.0f / (float)Rr);
    __syncthreads();
    {
      const float4* src = (const float4*)(Ap + (size_t)(m0 + arow) * Dd + kc + aq * 8);
      float4 v0 = src[0], v1 = src[1];
      float4* d0 = (float4*)&Asm[arow][aq * 8];
      d0[0] = make_float4(v0.x * sA, v0.y * sA, v0.z * sA, v0.w * sA);
      d0[1] = make_float4(v1.x * sA, v1.y * sA, v1.z * sA, v1.w * sA);
    }
#pragma unroll
    for (int j = 0; j < 4; j++) {
      int idx = t + j * 256;
      int k = idx >> 5, d4 = idx & 31;
      *(float4*)&Bsm[k][d4 * 4] = *(const float4*)(Wp + (size_t)(kc + k) * Dd + d4 * 4);
    }
    __syncthreads();
#pragma unroll
    for (int kk = 0; kk < 32; kk += 4) {
      float4 af[8], bf[4];
#pragma unroll
      for (int r = 0; r < 8; r++) af[r] = *(const float4*)&Asm[rg * 8 + r][kk];
#pragma unroll
      for (int j = 0; j < 4; j++) bf[j] = *(const float4*)&Bsm[kk + j][cg * 4];
#pragma unroll
      for (int r = 0; r < 8; r++) {
        const float* ap = (const float*)&af[r];
#pragma unroll
        for (int j = 0; j < 4; j++) {
          const float* bp = (const float*)&bf[j];
          acc[r][0] += ap[j] * bp[0];
          acc[r][1] += ap[j] * bp[1];
          acc[r][2] += ap[j] * bp[2];
          acc[r][3] += ap[j] * bp[3];
        }
      }
    }
  }
  float4 vb1 = *(const float4*)(bsrc + cg * 4);
  float4 vb2 = *(const float4*)(bdst + cg * 4);
  float4 vbf = *(const float4*)(bfc + cg * 4);
  float ps[4] = {0.f, 0.f, 0.f, 0.f}, ps2[4] = {0.f, 0.f, 0.f, 0.f};
#pragma unroll
  for (int r = 0; r < 8; r++) {
    int row = m0 + rg * 8 + r;
    size_t o = (size_t)row * Dd + cg * 4;
    float s1 = sco[row] * (1.0f / (float)Rr), s2 = sci[row] * (1.0f / (float)Rr);
    float4 v;
    v.x = acc[r][0] + s1 * vb1.x + s2 * vb2.x + alpha * vbf.x;
    v.y = acc[r][1] + s1 * vb1.y + s2 * vb2.y + alpha * vbf.y;
    v.z = acc[r][2] + s1 * vb1.z + s2 * vb2.z + alpha * vbf.z;
    v.w = acc[r][3] + s1 * vb1.w + s2 * vb2.w + alpha * vbf.w;
    *(float4*)(pre + o) = v;
    ps[0] += v.x; ps[1] += v.y; ps[2] += v.z; ps[3] += v.w;
    ps2[0] += v.x * v.x; ps2[1] += v.y * v.y; ps2[2] += v.z * v.z; ps2[3] += v.w * v.w;
  }
  if (t < 128) { lsum[t] = 0.f; lsum2[t] = 0.f; }
  __syncthreads();
#pragma unroll
  for (int j = 0; j < 4; j++) {
    atomicAdd(&lsum[cg * 4 + j], ps[j]);
    atomicAdd(&lsum2[cg * 4 + j], ps2[j]);
  }
  __syncthreads();
  if (t < 128) atomicAdd(&bnsum[t], lsum[t]);
  else if (t < 256) atomicAdd(&bnsum[t], lsum2[t - 128]);
}

__global__ void k_bnapply(const float* __restrict__ pre, const float* __restrict__ sums,
                          const float* __restrict__ gamma, const float* __restrict__ beta,
                          float* __restrict__ hout, float* __restrict__ gs, int do_gs) {
  __shared__ float ls[256];
  int c = threadIdx.x & 127, sub = threadIdx.x >> 7;
  float mu = sums[c] * (1.0f / (float)Nn);
  float var = sums[c + 128] * (1.0f / (float)Nn) - mu * mu;
  float sc = gamma[c] / sqrtf(var + BN_EPS);
  float bt = beta[c];
  float g = 0.f;
  for (int n = blockIdx.x * 2 + sub; n < Nn; n += gridDim.x * 2) {
    float v = (pre[(size_t)n * Dd + c] - mu) * sc + bt;
    v = fmaxf(v, 0.f);
    hout[(size_t)n * Dd + c] = v;
    g += v;
  }
  if (do_gs) {
    ls[threadIdx.x] = g;
    __syncthreads();
    if (sub == 0) atomicAdd(&gs[c], (ls[c] + ls[c + 128]) * (1.0f / (float)Nn));
  }
}

// logp + folded c_in/c_out outputs (one block per node)
__global__ __launch_bounds__(64) void k_logp(const float* __restrict__ ph0, const float* __restrict__ ph1,
                      const float* __restrict__ Wlin, const float* __restrict__ blin,
                      const float* __restrict__ ci_acc, const float* __restrict__ co_acc,
                      float* __restrict__ cins, float* __restrict__ couts,
                      float* __restrict__ logp) {
  __shared__ float jk[Dd];
  __shared__ float lg[Cc];
  int n = blockIdx.x, t = threadIdx.x;
  if (t == 63) {
    cins[n] = ci_acc[n] * (1.0f / (float)(Ll * Rr));
    couts[n] = co_acc[n] * (1.0f / (float)(Ll * Rr));
  }
  for (int d = t; d < Dd; d += 64) jk[d] = fmaxf(ph0[(size_t)n * Dd + d], ph1[(size_t)n * Dd + d]);
  __syncthreads();
  if (t < Cc) {
    float acc = blin[t];
    for (int k = 0; k < Dd; k++) acc += jk[k] * Wlin[k * Cc + t];
    lg[t] = acc;
  }
  __syncthreads();
  float m = -1e30f;
  for (int c = 0; c < Cc; c++) m = fmaxf(m, lg[c]);
  float s = 0.f;
  for (int c = 0; c < Cc; c++) s += expf(lg[c] - m);
  float lse = m + logf(s);
  if (t < Cc) logp[(size_t)n * Cc + t] = lg[t] - lse;
}

// ---------------- host ----------------
extern "C" void kernel_launch(void* const* d_in, const int* in_sizes, int n_in,
                              void* d_out, int out_size, void* d_ws, size_t ws_size,
                              hipStream_t stream) {
  const float* x      = (const float*)d_in[0];
  const int*   ei     = (const int*)d_in[1];
  const float* W_src  = (const float*)d_in[2];
  const float* b_src  = (const float*)d_in[3];
  const float* W_dst  = (const float*)d_in[4];
  const float* b_dst  = (const float*)d_in[5];
  const float* W_outf = (const float*)d_in[6];
  const float* b_outf = (const float*)d_in[7];
  const float* W_inf  = (const float*)d_in[8];
  const float* b_inf  = (const float*)d_in[9];
  const float* W_fc   = (const float*)d_in[10];
  const float* b_fc   = (const float*)d_in[11];
  const float* gamma  = (const float*)d_in[12];
  const float* beta   = (const float*)d_in[13];
  const float* oemb   = (const float*)d_in[14];
  const float* iemb   = (const float*)d_in[15];
  const float* omask  = (const float*)d_in[16];
  const float* omaskb = (const float*)d_in[17];
  const float* imask  = (const float*)d_in[18];
  const float* imaskb = (const float*)d_in[19];
  const float* alphap = (const float*)d_in[20];
  const float* taup   = (const float*)d_in[21];
  const float* Wlin   = (const float*)d_in[22];
  const float* blin   = (const float*)d_in[23];

  float* out   = (float*)d_out;
  float* logp  = out;
  float* cins  = logp + (size_t)Nn * Cc;
  float* couts = cins + Nn;
  float* ph0   = couts + Nn;
  float* ph1   = ph0 + (size_t)Nn * Dd;
  float* nh0   = ph1 + (size_t)Nn * Dd;
  float* nh1   = nh0 + (size_t)Nn * Dd;
  float* gs0   = nh1 + (size_t)Nn * Dd;
  float* gs1   = gs0 + Dd;

  char* p = (char*)d_ws;
  auto alloc = [&](size_t bytes) -> void* {
    void* q = (void*)p;
    p += (bytes + 255) & ~(size_t)255;
    return q;
  };
  float* pre   = (float*)alloc((size_t)Nn * Dd * 4);
  float* Tout  = (float*)alloc((size_t)Nn * Dd * 4);
  float* Tin   = (float*)alloc((size_t)Nn * Dd * 4);
  float* hperm = (float*)alloc((size_t)Nn * Dd * 4);
  unsigned* pbuf = (unsigned*)alloc((size_t)6 * Ee * 4);
  size_t qwords = (size_t)6 * Ee;
  size_t pwords = (size_t)(6 * 3 * HR_SB) * HR_PAD;
  unsigned* qbuf = (unsigned*)alloc((qwords > pwords ? qwords : pwords) * 4);
  int* partials = (int*)qbuf;
  int* csr_off = (int*)alloc((size_t)Rr * (Nn + 1) * 4);
  int* csc_off = (int*)alloc((size_t)Rr * (Nn + 1) * 4);
  int* odeg    = (int*)alloc((size_t)Rr * Nn * 4);
  int* ideg    = (int*)alloc((size_t)Rr * Nn * 4);
  float* ods   = (float*)alloc((size_t)Rr * Nn * 4);
  float* ids   = (float*)alloc((size_t)Rr * Nn * 4);
  int* odix    = (int*)alloc((size_t)Rr * Nn * 4);
  int* idix    = (int*)alloc((size_t)Rr * Nn * 4);
  float4* aux  = (float4*)alloc((size_t)Nn * 16);
  float4* auxrd = (float4*)alloc((size_t)6 * Nn * 16);
  float* sco   = (float*)alloc((size_t)Nn * 4 * 2);
  float* sci   = sco + Nn;
  float* coacc = (float*)alloc((size_t)Nn * 4 * 2);
  float* ciacc = coacc + Nn;
  float* luto  = (float*)alloc((size_t)2 * MAXD * 4);
  float* luti  = (float*)alloc((size_t)2 * MAXD * 4);
  float* bnsum = (float*)alloc(256 * 4);
  unsigned* kbuf0 = (unsigned*)alloc((size_t)2 * Nn * 4);
  unsigned* kbuf1 = (unsigned*)alloc((size_t)2 * Nn * 4);
  int* vbuf0 = (int*)alloc((size_t)2 * Nn * 4);
  int* vbuf1 = (int*)alloc((size_t)2 * Nn * 4);
  int* rhist = (int*)alloc((size_t)2 * (RB_H + 1) * 4);
  int* rscan = (int*)alloc((size_t)2 * (RB_H + 1) * 4);
  int* ehist = (int*)alloc((size_t)6 * EB_H * 4);
  int* escan = (int*)alloc((size_t)6 * (EB_H + 1) * 4);

  // ---- graph structure ----
  k_hist2<<<6 * 3 * HR_SB, 256, 0, stream>>>(ei, partials);
  k_hreduce<<<(6 * Nn + 255) / 256, 256, 0, stream>>>(partials, odeg, ideg);
  k_degnorm<<<(Rr * Nn + 255) / 256, 256, 0, stream>>>(odeg, ideg, ods, ids, odix, idix);
  k_scan6<<<6, 1024, 0, stream>>>(odeg, ideg, csr_off, csc_off);
  k_pack<<<(3 * Ee + 255) / 256, 256, 0, stream>>>(ei, pbuf, pbuf + (size_t)3 * Ee);
  k_ehist<<<6 * EB_NB, 256, 0, stream>>>(pbuf, ehist, 16);
  k_escan6<<<6, 1024, 0, stream>>>(ehist, escan);
  k_escatter<<<6 * EB_NB, 256, 0, stream>>>(pbuf, escan, 16, qbuf);
  k_ehist<<<6 * EB_NB, 256, 0, stream>>>(qbuf, ehist, 24);
  k_escan6<<<6, 1024, 0, stream>>>(ehist, escan);
  k_escatter<<<6 * EB_NB, 256, 0, stream>>>(qbuf, escan, 24, pbuf);
  hipMemsetAsync(coacc, 0, (size_t)Nn * 4 * 2, stream);
  k_lut2<<<2 * MAXD / 4, 256, 0, stream>>>(oemb, iemb, W_outf, W_inf, luto, luti);

  // ---- both permutations, batched (seeds 100 & 101) ----
  auto radix4b = [&]() {
    for (int pass = 0; pass < 4; pass++) {
      const unsigned* ik = (pass & 1) ? kbuf1 : kbuf0;
      const int*      iv = (pass & 1) ? vbuf1 : vbuf0;
      unsigned*       ok = (pass & 1) ? kbuf0 : kbuf1;
      int*            ov = (pass & 1) ? vbuf0 : vbuf1;
      int shift = pass * 8;
      k_rhist2<<<2 * RB_NB, 256, 0, stream>>>(ik, rhist, shift);
      k_scanP<<<2, 1024, 0, stream>>>(rhist, rscan);
      k_rscatter2<<<2 * RB_NB, 256, 0, stream>>>(ik, iv, rscan, shift, ok, ov);
    }
  };
  k_genkeys2<<<(2 * Nn + 255) / 256, 256, 0, stream>>>(kbuf0, 100u, 101u, 1, vbuf0, 1);
  radix4b();
  k_genkeys2<<<(2 * Nn + 255) / 256, 256, 0, stream>>>(kbuf0, 100u, 101u, 2, vbuf0, 0);
  radix4b();

  auto conv = [&](int l, const float* hin, float* hout, float* gs, int is_pos) {
    const float* Wfo = W_outf + l * Dd;
    const float* Wfi = W_inf + l * Dd;
    k_rowscalar<<<Nn / 4, 256, 0, stream>>>(hin, Wfo, Wfi, aux, ods, ids, auxrd, bnsum,
                                            is_pos ? gs : nullptr);
    for (int r = 0; r < Rr; r++) {
      k_csrdir3<<<Nn / 2, 256, 0, stream>>>(csr_off + r * (Nn + 1), pbuf + (size_t)r * Ee,
                                            csc_off + r * (Nn + 1), pbuf + (size_t)(3 + r) * Ee,
                                            ods + r * Nn, ids + r * Nn,
                                            auxrd + (size_t)(2 * r) * Nn,
                                            auxrd + (size_t)(2 * r + 1) * Nn,
                                            aux, hin, Wfo, Wfi,
                                            luto + l * MAXD, luti + l * MAXD,
                                            odix + r * Nn, idix + r * Nn,
                                            b_outf + l, b_inf + l, taup,
                                            omask + (size_t)r * Nn, omaskb + (size_t)r * Nn,
                                            imask + (size_t)r * Nn, imaskb + (size_t)r * Nn,
                                            Tout, Tin, sco, sci, coacc, ciacc,
                                            r == 0 ? 1 : 0, is_pos);
    }
    k_gemmconv<<<Nn / 64, 256, 0, stream>>>(Tout, Tin, hin,
                                            W_src + (size_t)l * Dd * Dd, W_dst + (size_t)l * Dd * Dd,
                                            W_fc + (size_t)l * Dd * Dd,
                                            b_src + l * Dd, b_dst + l * Dd, b_fc + l * Dd,
                                            sco, sci, alphap, pre, bnsum);
    k_bnapply<<<256, 256, 0, stream>>>(pre, bnsum, gamma + l * Dd, beta + l * Dd, hout, gs, is_pos);
  };

  // ---- layer 0 ----
  conv(0, x, ph0, gs0, 1);
  k_permrows<<<Nn / 8, 256, 0, stream>>>(x, vbuf0, hperm);
  conv(0, hperm, nh0, nullptr, 0);

  // ---- layer 1 ----
  conv(1, ph0, ph1, gs1, 1);
  k_permrows<<<Nn / 8, 256, 0, stream>>>(nh0, vbuf0 + Nn, hperm);
  conv(1, hperm, nh1, nullptr, 0);

  // ---- outputs ----
  k_logp<<<Nn, 64, 0, stream>>>(ph0, ph1, Wlin, blin, ciacc, coacc, cins, couts, logp);
}

// Round 14
// 2162.490 us; speedup vs baseline: 1.2632x; 1.0531x over previous
//
#include <hip/hip_runtime.h>

// ---------------- problem constants ----------------
constexpr int Nn = 40000;
constexpr int Dd = 128;
constexpr int Rr = 3;
constexpr int Ee = 640000;
constexpr int Ll = 2;
constexpr int Cc = 40;
constexpr int MAXD = 512;
constexpr float BN_EPS = 1e-5f;

// radix sort geometry (permutation keys, 2 batched segments)
constexpr int RB_ELEMS = 1024;
constexpr int RB_NB = (Nn + RB_ELEMS - 1) / RB_ELEMS; // 40 blocks per segment
constexpr int RB_BINS = 256;
constexpr int RB_H = RB_BINS * RB_NB;                 // hist entries per segment

// edge sort geometry
constexpr int EB_ELEMS = 4096;
constexpr int EB_NB = (Ee + EB_ELEMS - 1) / EB_ELEMS; // 157
constexpr int EB_H = 256 * EB_NB;                     // hist entries per array

// histogram geometry
constexpr int HR_BINS = 13334;  // ceil(Nn/3)
constexpr int HR_PAD = 13344;
constexpr int HR_SB = 16;
constexpr int HR_CHUNK = (Ee + HR_SB - 1) / HR_SB;

// ---------------- threefry-2x32 (JAX-compatible) ----------------
__device__ __forceinline__ unsigned rotl32(unsigned x, int d) { return (x << d) | (x >> (32 - d)); }

__device__ void threefry2x32(unsigned k0, unsigned k1, unsigned c0, unsigned c1,
                             unsigned& o0, unsigned& o1) {
  unsigned ks2 = k0 ^ k1 ^ 0x1BD11BDAu;
  unsigned x0 = c0 + k0, x1 = c1 + k1;
#define TFR4(a,b,c,d2) \
  x0 += x1; x1 = rotl32(x1,a);  x1 ^= x0; \
  x0 += x1; x1 = rotl32(x1,b);  x1 ^= x0; \
  x0 += x1; x1 = rotl32(x1,c);  x1 ^= x0; \
  x0 += x1; x1 = rotl32(x1,d2); x1 ^= x0;
  TFR4(13,15,26,6);  x0 += k1;  x1 += ks2 + 1u;
  TFR4(17,29,16,24); x0 += ks2; x1 += k0 + 2u;
  TFR4(13,15,26,6);  x0 += k0;  x1 += k1 + 3u;
  TFR4(17,29,16,24); x0 += k1;  x1 += ks2 + 4u;
  TFR4(13,15,26,6);  x0 += ks2; x1 += k0 + 5u;
#undef TFR4
  o0 = x0; o1 = x1;
}

// batched over 2 segments (seeds seed0, seed1); local index per segment
__global__ void k_genkeys2(unsigned* __restrict__ keys, unsigned seed0, unsigned seed1,
                           int rounds, int* __restrict__ vout, int doIota) {
  int i = blockIdx.x * blockDim.x + threadIdx.x;
  if (i >= 2 * Nn) return;
  int seg = i / Nn, li = i - seg * Nn;
  unsigned seed = seg ? seed1 : seed0;
  unsigned k0 = 0u, k1 = seed, sk0 = 0u, sk1 = 0u;
  for (int rd = 0; rd < rounds; rd++) {
    unsigned a0, a1, b0, b1;
    threefry2x32(k0, k1, 0u, 0u, a0, a1);
    threefry2x32(k0, k1, 0u, 1u, b0, b1);
    sk0 = b0; sk1 = b1;
    k0 = a0; k1 = a1;
  }
  unsigned o0, o1;
  threefry2x32(sk0, sk1, 0u, (unsigned)li, o0, o1);
  keys[i] = o0 ^ o1;
  if (doIota) vout[i] = li;
}

// ---------------- LSD radix sort for permutations (stable, 2 segments) ----------------
__global__ void k_rhist2(const unsigned* __restrict__ keys, int* __restrict__ hist, int shift) {
  __shared__ int lh[RB_BINS];
  int a = blockIdx.x / RB_NB, blk = blockIdx.x % RB_NB;
  const unsigned* src = keys + (size_t)a * Nn;
  int t = threadIdx.x;
  lh[t] = 0;
  __syncthreads();
  int base = blk * RB_ELEMS;
  for (int i = t; i < RB_ELEMS; i += 256) {
    int g = base + i;
    if (g < Nn) atomicAdd(&lh[(src[g] >> shift) & 255], 1);
  }
  __syncthreads();
  hist[(size_t)a * RB_H + t * RB_NB + blk] = lh[t];
}

__device__ void scan_body(const int* cnt, int* off, int n, int items) {
  int t = threadIdx.x;
  int lo = t * items, hi = min(lo + items, n);
  int s = 0;
  for (int i = lo; i < hi; i++) s += cnt[i];
  int lane = t & 63, wid = t >> 6;
  int sc = s;
#pragma unroll
  for (int o = 1; o < 64; o <<= 1) {
    int v = __shfl_up(sc, o);
    if (lane >= o) sc += v;
  }
  __shared__ int wsum[16], woff[16];
  if (lane == 63) wsum[wid] = sc;
  __syncthreads();
  if (t == 0) {
    int a = 0;
    for (int w = 0; w < 16; w++) { woff[w] = a; a += wsum[w]; }
    off[n] = a;
  }
  __syncthreads();
  int run = woff[wid] + sc - s;
  for (int i = lo; i < hi; i++) {
    int v = cnt[i];
    off[i] = run;
    run += v;
  }
}

// 2-segment scan for the perm-sort histograms
__global__ __launch_bounds__(1024) void k_scanP(const int* __restrict__ hist, int* __restrict__ esc) {
  int a = blockIdx.x;
  scan_body(hist + (size_t)a * RB_H, esc + (size_t)a * (RB_H + 1), RB_H, (RB_H + 1023) / 1024);
}

// 6 independent scans (3 csr + 3 csc) in one dispatch
__global__ __launch_bounds__(1024) void k_scan6(const int* __restrict__ odeg, const int* __restrict__ ideg,
                                                int* __restrict__ csr_off, int* __restrict__ csc_off) {
  int b = blockIdx.x;
  const int* cnt = (b < 3) ? (odeg + b * Nn) : (ideg + (b - 3) * Nn);
  int* off = (b < 3) ? (csr_off + b * (Nn + 1)) : (csc_off + (b - 3) * (Nn + 1));
  scan_body(cnt, off, Nn, (Nn + 1023) / 1024);
}

__global__ void k_rscatter2(const unsigned* __restrict__ keys, const int* __restrict__ vals,
                            const int* __restrict__ scanned, int shift,
                            unsigned* __restrict__ okeys, int* __restrict__ ovals) {
  __shared__ int running[RB_BINS];
  __shared__ int wcount[4][RB_BINS];
  __shared__ int dbase[RB_BINS];
  int a = blockIdx.x / RB_NB, blk = blockIdx.x % RB_NB;
  const unsigned* ksrc = keys + (size_t)a * Nn;
  const int* vsrc = vals + (size_t)a * Nn;
  unsigned* kdst = okeys + (size_t)a * Nn;
  int* vdst = ovals + (size_t)a * Nn;
  int t = threadIdx.x;
  int lane = t & 63, w = t >> 6;
  running[t] = 0;
  dbase[t] = scanned[(size_t)a * (RB_H + 1) + t * RB_NB + blk];
  int base = blk * RB_ELEMS;
  for (int rnd = 0; rnd < 4; rnd++) {
#pragma unroll
    for (int q = 0; q < 4; q++) wcount[q][t] = 0;
    __syncthreads();
    int g = base + rnd * 256 + t;
    bool valid = g < Nn;
    unsigned key = valid ? ksrc[g] : 0u;
    int d = (key >> shift) & 255;
    unsigned long long bb = __ballot(valid);
    unsigned long long mask = bb;
#pragma unroll
    for (int k = 0; k < 8; k++) {
      bool b = (d >> k) & 1;
      unsigned long long tt = __ballot(b && valid);
      mask &= b ? tt : ~tt;
    }
    mask &= bb;
    int riw = __popcll(mask & ((1ull << lane) - 1ull));
    int cnt_ = __popcll(mask);
    if (valid && riw == 0) wcount[w][d] = cnt_;
    __syncthreads();
    if (valid) {
      int prior = 0;
#pragma unroll
      for (int ww = 0; ww < 4; ww++) if (ww < w) prior += wcount[ww][d];
      int gp = dbase[d] + running[d] + prior + riw;
      kdst[gp] = key;
      vdst[gp] = vsrc[g];
    }
    __syncthreads();
    running[t] += wcount[0][t] + wcount[1][t] + wcount[2][t] + wcount[3][t];
    __syncthreads();
  }
}

__global__ void k_permrows(const float* __restrict__ src, const int* __restrict__ perm,
                           float* __restrict__ dst) {
  int row = blockIdx.x * 8 + (threadIdx.x >> 5);
  int lane = threadIdx.x & 31;
  if (row >= Nn) return;
  int p = perm[row];
  ((float4*)(dst + (size_t)row * Dd))[lane] = ((const float4*)(src + (size_t)p * Dd))[lane];
}

// ---------------- graph structure (atomic-free histogram) ----------------
__global__ __launch_bounds__(256) void k_hist2(const int* __restrict__ ei, int* __restrict__ partials) {
  __shared__ int lh[HR_BINS];
  int bid = blockIdx.x;  // j*(3*HR_SB) + range*HR_SB + sb
  int sb = bid % HR_SB;
  int range = (bid / HR_SB) % 3;
  int j = bid / (3 * HR_SB);
  int rel = j >> 1, which = j & 1;
  const int* src = ei + (size_t)rel * 2 * Ee + (size_t)which * Ee;
  int lo = range * HR_BINS;
  for (int i = threadIdx.x; i < HR_BINS; i += 256) lh[i] = 0;
  __syncthreads();
  int e0 = sb * HR_CHUNK, e1 = min(e0 + HR_CHUNK, Ee);
  for (int e = e0 + threadIdx.x; e < e1; e += 256) {
    int v = src[e] - lo;
    if (v >= 0 && v < HR_BINS) atomicAdd(&lh[v], 1);
  }
  __syncthreads();
  int* dst = partials + (size_t)bid * HR_PAD;
  for (int i = threadIdx.x; i < HR_BINS; i += 256) dst[i] = lh[i];
}

__global__ void k_hreduce(const int* __restrict__ partials, int* __restrict__ odeg,
                          int* __restrict__ ideg) {
  int idx = blockIdx.x * 256 + threadIdx.x;
  if (idx >= 6 * Nn) return;
  int j = idx / Nn, bin = idx - j * Nn;
  int range = bin / HR_BINS, off = bin - range * HR_BINS;
  const int* p = partials + (size_t)((j * 3 + range) * HR_SB) * HR_PAD + off;
  int sum = 0;
#pragma unroll
  for (int b = 0; b < HR_SB; b++) sum += p[(size_t)b * HR_PAD];
  int rel = j >> 1;
  (j & 1 ? ideg : odeg)[rel * Nn + bin] = sum;
}

__global__ void k_degnorm(const int* __restrict__ odeg, const int* __restrict__ ideg,
                          float* __restrict__ ods, float* __restrict__ ids,
                          int* __restrict__ odix, int* __restrict__ idix) {
  int idx = blockIdx.x * blockDim.x + threadIdx.x;
  if (idx >= Rr * Nn) return;
  int od = odeg[idx], id_ = ideg[idx];
  ods[idx] = od > 0 ? 1.0f / sqrtf((float)od) : 0.0f;
  ids[idx] = id_ > 0 ? 1.0f / sqrtf((float)id_) : 0.0f;
  odix[idx] = od < MAXD - 1 ? od : MAXD - 1;
  idix[idx] = id_ < MAXD - 1 ? id_ : MAXD - 1;
}

// pack edges: pcsr[rel][e] = (row<<16)|col ; pcsc[rel][e] = (col<<16)|row
__global__ void k_pack(const int* __restrict__ ei, unsigned* __restrict__ pcsr,
                       unsigned* __restrict__ pcsc) {
  int idx = blockIdx.x * 256 + threadIdx.x;
  if (idx >= 3 * Ee) return;
  int r = idx / Ee, e = idx - r * Ee;
  const int* base = ei + (size_t)r * 2 * Ee;
  unsigned rw = (unsigned)base[e], cl = (unsigned)base[Ee + e];
  pcsr[idx] = (rw << 16) | cl;
  pcsc[idx] = (cl << 16) | rw;
}

// edge radix: histogram per (array, block)
__global__ __launch_bounds__(256) void k_ehist(const unsigned* __restrict__ pin,
                                               int* __restrict__ hist, int shift) {
  __shared__ int lh[256];
  int a = blockIdx.x / EB_NB, blk = blockIdx.x % EB_NB;
  const unsigned* src = pin + (size_t)a * Ee;
  lh[threadIdx.x] = 0;
  __syncthreads();
  int base = blk * EB_ELEMS;
  for (int i = threadIdx.x; i < EB_ELEMS; i += 256) {
    int g = base + i;
    if (g < Ee) atomicAdd(&lh[(src[g] >> shift) & 255], 1);
  }
  __syncthreads();
  hist[(size_t)a * EB_H + threadIdx.x * EB_NB + blk] = lh[threadIdx.x];
}

// 6 scans of EB_H entries each
__global__ __launch_bounds__(1024) void k_escan6(const int* __restrict__ hist, int* __restrict__ esc) {
  int a = blockIdx.x;
  scan_body(hist + (size_t)a * EB_H, esc + (size_t)a * (EB_H + 1), EB_H, (EB_H + 1023) / 1024);
}

// stable scatter of packed edges (16 rounds of 256)
__global__ __launch_bounds__(256) void k_escatter(const unsigned* __restrict__ pin,
                                                  const int* __restrict__ esc, int shift,
                                                  unsigned* __restrict__ pout) {
  __shared__ int running[256];
  __shared__ int wcount[4][256];
  __shared__ int dbase[256];
  int a = blockIdx.x / EB_NB, blk = blockIdx.x % EB_NB;
  const unsigned* src = pin + (size_t)a * Ee;
  unsigned* dst = pout + (size_t)a * Ee;
  int t = threadIdx.x;
  int lane = t & 63, w = t >> 6;
  running[t] = 0;
  dbase[t] = esc[(size_t)a * (EB_H + 1) + t * EB_NB + blk];
  int base = blk * EB_ELEMS;
  for (int rnd = 0; rnd < 16; rnd++) {
#pragma unroll
    for (int q = 0; q < 4; q++) wcount[q][t] = 0;
    __syncthreads();
    int g = base + rnd * 256 + t;
    bool valid = g < Ee;
    unsigned key = valid ? src[g] : 0u;
    int d = (key >> shift) & 255;
    unsigned long long bb = __ballot(valid);
    unsigned long long mask = bb;
#pragma unroll
    for (int k = 0; k < 8; k++) {
      bool b = (d >> k) & 1;
      unsigned long long tt = __ballot(b && valid);
      mask &= b ? tt : ~tt;
    }
    mask &= bb;
    int riw = __popcll(mask & ((1ull << lane) - 1ull));
    int cnt_ = __popcll(mask);
    if (valid && riw == 0) wcount[w][d] = cnt_;
    __syncthreads();
    if (valid) {
      int prior = 0;
#pragma unroll
      for (int ww = 0; ww < 4; ww++) if (ww < w) prior += wcount[ww][d];
      int gp = dbase[d] + running[d] + prior + riw;
      dst[gp] = key;
    }
    __syncthreads();
    running[t] += wcount[0][t] + wcount[1][t] + wcount[2][t] + wcount[3][t];
    __syncthreads();
  }
}

// ---------------- per-conv kernels (pos+neg batched: mat = 0/1) ----------------
// aux[mat][n] = (rinv, qo, qi, 0); auxrd[mat][(2r+dir)][n] = (nbr-scale, rinv, q);
// block 0 zeroes bnsum[512] (and gs for the pos matrix).
__global__ void k_rowscalar(const float* __restrict__ hA, const float* __restrict__ hB,
                            const float* __restrict__ Wfo, const float* __restrict__ Wfi,
                            float4* __restrict__ aux,
                            const float* __restrict__ ods, const float* __restrict__ ids,
                            float4* __restrict__ auxrd,
                            float* __restrict__ bnsum, float* __restrict__ gs) {
  if (blockIdx.x == 0) {
    bnsum[threadIdx.x] = 0.f;
    bnsum[256 + threadIdx.x] = 0.f;
    if (gs != nullptr && threadIdx.x < Dd) gs[threadIdx.x] = 0.f;
  }
  int half = Nn / 4;
  int mat = blockIdx.x >= half ? 1 : 0;
  int lb = blockIdx.x - mat * half;
  const float* h = mat ? hB : hA;
  int wid = (lb * blockDim.x + threadIdx.x) >> 6;
  int lane = threadIdx.x & 63;
  if (wid >= Nn) return;
  float2 a = ((const float2*)(h + (size_t)wid * Dd))[lane];
  float2 wo = ((const float2*)Wfo)[lane];
  float2 wi = ((const float2*)Wfi)[lane];
  float l1 = fabsf(a.x) + fabsf(a.y);
  float so = a.x * a.x * wo.x + a.y * a.y * wo.y;
  float si = a.x * a.x * wi.x + a.y * a.y * wi.y;
#pragma unroll
  for (int o = 32; o; o >>= 1) {
    l1 += __shfl_xor(l1, o);
    so += __shfl_xor(so, o);
    si += __shfl_xor(si, o);
  }
  if (lane == 0) {
    float ri = 1.0f / (l1 + 1e-12f);
    float qo = ri * ri * so, qi = ri * ri * si;
    aux[(size_t)mat * Nn + wid] = make_float4(ri, qo, qi, 0.f);
    float4* ard = auxrd + (size_t)mat * 6 * Nn;
#pragma unroll
    for (int r = 0; r < Rr; r++) {
      ard[(size_t)(2 * r) * Nn + wid] = make_float4(ids[r * Nn + wid], ri, qo, 0.f);
      ard[(size_t)(2 * r + 1) * Nn + wid] = make_float4(ods[r * Nn + wid], ri, qi, 0.f);
    }
  }
}

// both layers' LUTs in one dispatch: luto/luti are [2][MAXD]
__global__ void k_lut2(const float* __restrict__ eo, const float* __restrict__ ei_,
                       const float* __restrict__ W_outf, const float* __restrict__ W_inf,
                       float* __restrict__ luto, float* __restrict__ luti) {
  int wid = (blockIdx.x * blockDim.x + threadIdx.x) >> 6;
  int lane = threadIdx.x & 63;
  if (wid >= 2 * MAXD) return;
  int l = wid >> 9, k = wid & (MAXD - 1);
  float2 a = ((const float2*)(eo + ((size_t)l * MAXD + k) * Dd))[lane];
  float2 b = ((const float2*)(ei_ + ((size_t)l * MAXD + k) * Dd))[lane];
  float2 wo = ((const float2*)(W_outf + l * Dd))[lane];
  float2 wi = ((const float2*)(W_inf + l * Dd))[lane];
  float so = a.x * wo.x + a.y * wo.y;
  float si = b.x * wi.x + b.y * wi.y;
#pragma unroll
  for (int o = 32; o; o >>= 1) { so += __shfl_xor(so, o); si += __shfl_xor(si, o); }
  if (lane == 0) { luto[wid] = so; luti[wid] = si; }
}

// fused gather + score + T accumulation, pos+neg batched.
// 256 threads = 4 waves = 2 nodes x 2 dirs; grid = 2*(Nn/2).
__global__ __launch_bounds__(256) void k_csrdir3(
    const int* __restrict__ csr_off, const unsigned* __restrict__ pcsr,
    const int* __restrict__ csc_off, const unsigned* __restrict__ pcsc,
    const float* __restrict__ ods_r, const float* __restrict__ ids_r,
    const float4* __restrict__ auxrd_base, int rel,
    const float4* __restrict__ aux_base,
    const float* __restrict__ hA, const float* __restrict__ hB,
    const float* __restrict__ Wfo, const float* __restrict__ Wfi,
    const float* __restrict__ luto, const float* __restrict__ luti,
    const int* __restrict__ odix, const int* __restrict__ idix,
    const float* __restrict__ bo, const float* __restrict__ bi,
    const float* __restrict__ taup,
    const float* __restrict__ omask, const float* __restrict__ omaskb,
    const float* __restrict__ imask, const float* __restrict__ imaskb,
    float* __restrict__ Tout_base, float* __restrict__ Tin_base,
    float* __restrict__ sco_base, float* __restrict__ sci_base,
    float* __restrict__ co_acc, float* __restrict__ ci_acc,
    int first) {
  __shared__ float lq[4], lp[4], lc[4];
  int halfg = Nn / 2;
  int mat = blockIdx.x >= halfg ? 1 : 0;
  int blk = blockIdx.x - mat * halfg;
  const float* h = mat ? hB : hA;
  const float4* aux = aux_base + (size_t)mat * Nn;
  float* sco = sco_base + (size_t)mat * Nn;
  float* sci = sci_base + (size_t)mat * Nn;
  int t = threadIdx.x;
  int wv = t >> 6, lane = t & 63;
  int dir = wv >> 1;
  int n = blk * 2 + (wv & 1);
  const int* off = dir ? csc_off : csr_off;
  const unsigned* nbrp = dir ? pcsc : pcsr;
  const float4* auxd = auxrd_base + (size_t)mat * 6 * Nn + (size_t)(2 * rel + dir) * Nn;
  float a_self = (dir ? ids_r : ods_r)[n];
  const float* Wf = dir ? Wfi : Wfo;
  int s0 = off[n], s1 = off[n + 1];
  int hl = lane & 31, half = lane >> 5;
  float4 wf4 = ((const float4*)Wf)[hl];
  float4 hn4 = ((const float4*)(h + (size_t)n * Dd))[hl];
  float rn = aux[n].x;
  float4 s = make_float4(0.f, 0.f, 0.f, 0.f);
  float4 pa = make_float4(0.f, 0.f, 0.f, 0.f);
  float qacc = 0.f;
  for (int base = s0; base < s1; base += 64) {
    int eidx = base + lane;
    bool valid = eidx < s1;
    int mi = valid ? (int)(nbrp[eidx] & 0xFFFFu) : 0;
    float4 av = valid ? auxd[mi] : make_float4(0.f, 0.f, 0.f, 0.f);
    int cnt = min(64, s1 - base);
#pragma unroll 4
    for (int j = half; j < cnt; j += 2) {
      int m = __shfl(mi, j);
      float sc = __shfl(av.x, j);
      float rm = __shfl(av.y, j);
      float qv = __shfl(av.z, j);
      float w = a_self * sc;
      float wrm = w * rm;
      float4 hv = ((const float4*)(h + (size_t)m * Dd))[hl];
      s.x += w * hv.x; s.y += w * hv.y; s.z += w * hv.z; s.w += w * hv.w;
      pa.x += wrm * hv.x; pa.y += wrm * hv.y; pa.z += wrm * hv.z; pa.w += wrm * hv.w;
      qacc += w * qv;
    }
  }
  s.x += __shfl_xor(s.x, 32); s.y += __shfl_xor(s.y, 32);
  s.z += __shfl_xor(s.z, 32); s.w += __shfl_xor(s.w, 32);
  pa.x += __shfl_xor(pa.x, 32); pa.y += __shfl_xor(pa.y, 32);
  pa.z += __shfl_xor(pa.z, 32); pa.w += __shfl_xor(pa.w, 32);
  qacc += __shfl_xor(qacc, 32);
  float pd = rn * (hn4.x * wf4.x * pa.x + hn4.y * wf4.y * pa.y +
                   hn4.z * wf4.z * pa.z + hn4.w * wf4.w * pa.w);
#pragma unroll
  for (int o = 16; o; o >>= 1) pd += __shfl_xor(pd, o);
  if (lane == 0) { lq[wv] = qacc; lp[wv] = pd; }
  __syncthreads();
  if (t < 2) {
    int nn = blk * 2 + t;
    float Qo_ = lq[t], Po_ = lp[t], Qi_ = lq[2 + t], Pi_ = lp[2 + t];
    float4 a2 = aux[nn];
    float im = (nn < Nn - 1) ? 1.0f : 0.0f;
    float so_ = luto[odix[nn]] + bo[0] - (Qo_ - 2.0f * Po_ + (2.0f - im) * a2.y);
    float si_ = luti[idix[nn]] + bi[0] - (Qi_ - 2.0f * Pi_ + (2.0f - im) * a2.z);
    float tt = expf(taup[0]) + 0.1f;
    float aa = so_ / tt, bb = si_ / tt;
    float mm = fmaxf(aa, bb);
    float ea = expf(aa - mm), eb = expf(bb - mm);
    float inv = 1.0f / (ea + eb);
    float co = ea * inv * omask[nn] + omaskb[nn];
    float ci = eb * inv * imask[nn] + imaskb[nn];
    lc[t] = co; lc[2 + t] = ci;
    if (first) { sco[nn] = co; sci[nn] = ci; }
    else       { sco[nn] += co; sci[nn] += ci; }
    if (mat == 0) { co_acc[nn] += co; ci_acc[nn] += ci; }
  }
  __syncthreads();
  float c = lc[wv];
  if (lane < 32) {
    float* T = (dir ? Tin_base : Tout_base) + (size_t)mat * Nn * Dd;
    size_t o = (size_t)n * Dd;
    float4 v = make_float4(c * s.x, c * s.y, c * s.z, c * s.w);
    if (!first) {
      float4 old = ((const float4*)(T + o))[hl];
      v.x += old.x; v.y += old.y; v.z += old.z; v.w += old.w;
    }
    ((float4*)(T + o))[hl] = v;
  }
}

// one GEMM per layer (pos+neg batched), K=384 (simple proven body):
// pre = (Tout/R)@Wsrc + (Tin/R)@Wdst + alpha*h@Wfc (+bias, +fused BN-stats)
__global__ __launch_bounds__(256) void k_gemmconv(
    const float* __restrict__ Tout_base, const float* __restrict__ Tin_base,
    const float* __restrict__ hA, const float* __restrict__ hB,
    const float* __restrict__ Wsrc, const float* __restrict__ Wdst, const float* __restrict__ Wfc,
    const float* __restrict__ bsrc, const float* __restrict__ bdst, const float* __restrict__ bfc,
    const float* __restrict__ sco_base, const float* __restrict__ sci_base,
    const float* __restrict__ alphap, float* __restrict__ pre_base, float* __restrict__ bnsum_base) {
  __shared__ float Asm[64][36];
  __shared__ float Bsm[32][132];
  __shared__ float lsum[128], lsum2[128];
  int halfg = Nn / 64;
  int mat = blockIdx.x >= halfg ? 1 : 0;
  int mb = blockIdx.x - mat * halfg;
  const float* Tout = Tout_base + (size_t)mat * Nn * Dd;
  const float* Tin = Tin_base + (size_t)mat * Nn * Dd;
  const float* h = mat ? hB : hA;
  const float* sco = sco_base + (size_t)mat * Nn;
  const float* sci = sci_base + (size_t)mat * Nn;
  float* pre = pre_base + (size_t)mat * Nn * Dd;
  float* bnsum = bnsum_base + (size_t)mat * 256;
  int t = threadIdx.x;
  int rg = t >> 5, cg = t & 31;
  int m0 = mb * 64;
  int arow = t >> 2, aq = t & 3;
  float alpha = alphap[0];
  float acc[8][4];
#pragma unroll
  for (int r = 0; r < 8; r++)
#pragma unroll
    for (int c = 0; c < 4; c++) acc[r][c] = 0.f;
  for (int kt = 0; kt < 12; kt++) {
    int sec = kt >> 2, kc = (kt & 3) * 32;
    const float* Ap = sec == 0 ? Tout : (sec == 1 ? Tin : h);
    const float* Wp = sec == 0 ? Wsrc : (sec == 1 ? Wdst : Wfc);
    float sA = (sec == 2) ? alpha : (1.0f / (float)Rr);
    __syncthreads();
    {
      const float4* src = (const float4*)(Ap + (size_t)(m0 + arow) * Dd + kc + aq * 8);
      float4 v0 = src[0], v1 = src[1];
      float4* d0 = (float4*)&Asm[arow][aq * 8];
      d0[0] = make_float4(v0.x * sA, v0.y * sA, v0.z * sA, v0.w * sA);
      d0[1] = make_float4(v1.x * sA, v1.y * sA, v1.z * sA, v1.w * sA);
    }
#pragma unroll
    for (int j = 0; j < 4; j++) {
      int idx = t + j * 256;
      int k = idx >> 5, d4 = idx & 31;
      *(float4*)&Bsm[k][d4 * 4] = *(const float4*)(Wp + (size_t)(kc + k) * Dd + d4 * 4);
    }
    __syncthreads();
#pragma unroll
    for (int kk = 0; kk < 32; kk += 4) {
      float4 af[8], bf[4];
#pragma unroll
      for (int r = 0; r < 8; r++) af[r] = *(const float4*)&Asm[rg * 8 + r][kk];
#pragma unroll
      for (int j = 0; j < 4; j++) bf[j] = *(const float4*)&Bsm[kk + j][cg * 4];
#pragma unroll
      for (int r = 0; r < 8; r++) {
        const float* ap = (const float*)&af[r];
#pragma unroll
        for (int j = 0; j < 4; j++) {
          const float* bp = (const float*)&bf[j];
          acc[r][0] += ap[j] * bp[0];
          acc[r][1] += ap[j] * bp[1];
          acc[r][2] += ap[j] * bp[2];
          acc[r][3] += ap[j] * bp[3];
        }
      }
    }
  }
  float4 vb1 = *(const float4*)(bsrc + cg * 4);
  float4 vb2 = *(const float4*)(bdst + cg * 4);
  float4 vbf = *(const float4*)(bfc + cg * 4);
  float ps[4] = {0.f, 0.f, 0.f, 0.f}, ps2[4] = {0.f, 0.f, 0.f, 0.f};
#pragma unroll
  for (int r = 0; r < 8; r++) {
    int row = m0 + rg * 8 + r;
    size_t o = (size_t)row * Dd + cg * 4;
    float s1 = sco[row] * (1.0f / (float)Rr), s2 = sci[row] * (1.0f / (float)Rr);
    float4 v;
    v.x = acc[r][0] + s1 * vb1.x + s2 * vb2.x + alpha * vbf.x;
    v.y = acc[r][1] + s1 * vb1.y + s2 * vb2.y + alpha * vbf.y;
    v.z = acc[r][2] + s1 * vb1.z + s2 * vb2.z + alpha * vbf.z;
    v.w = acc[r][3] + s1 * vb1.w + s2 * vb2.w + alpha * vbf.w;
    *(float4*)(pre + o) = v;
    ps[0] += v.x; ps[1] += v.y; ps[2] += v.z; ps[3] += v.w;
    ps2[0] += v.x * v.x; ps2[1] += v.y * v.y; ps2[2] += v.z * v.z; ps2[3] += v.w * v.w;
  }
  if (t < 128) { lsum[t] = 0.f; lsum2[t] = 0.f; }
  __syncthreads();
#pragma unroll
  for (int j = 0; j < 4; j++) {
    atomicAdd(&lsum[cg * 4 + j], ps[j]);
    atomicAdd(&lsum2[cg * 4 + j], ps2[j]);
  }
  __syncthreads();
  if (t < 128) atomicAdd(&bnsum[t], lsum[t]);
  else if (t < 256) atomicAdd(&bnsum[t], lsum2[t - 128]);
}

// BN apply + relu for both matrices; grid 512 (256 pos + 256 neg)
__global__ void k_bnapply(const float* __restrict__ pre_base, const float* __restrict__ bnsum_base,
                          const float* __restrict__ gamma, const float* __restrict__ beta,
                          float* __restrict__ houtA, float* __restrict__ houtB,
                          float* __restrict__ gs) {
  __shared__ float ls[256];
  int mat = blockIdx.x >= 256 ? 1 : 0;
  int blk = blockIdx.x - mat * 256;
  const float* pre = pre_base + (size_t)mat * Nn * Dd;
  const float* sums = bnsum_base + (size_t)mat * 256;
  float* hout = mat ? houtB : houtA;
  int c = threadIdx.x & 127, sub = threadIdx.x >> 7;
  float mu = sums[c] * (1.0f / (float)Nn);
  float var = sums[c + 128] * (1.0f / (float)Nn) - mu * mu;
  float sc = gamma[c] / sqrtf(var + BN_EPS);
  float bt = beta[c];
  float g = 0.f;
  for (int n = blk * 2 + sub; n < Nn; n += 512) {
    float v = (pre[(size_t)n * Dd + c] - mu) * sc + bt;
    v = fmaxf(v, 0.f);
    hout[(size_t)n * Dd + c] = v;
    g += v;
  }
  if (mat == 0) {
    ls[threadIdx.x] = g;
    __syncthreads();
    if (sub == 0) atomicAdd(&gs[c], (ls[c] + ls[c + 128]) * (1.0f / (float)Nn));
  }
}

// logp + folded c_in/c_out outputs (one block per node)
__global__ __launch_bounds__(64) void k_logp(const float* __restrict__ ph0, const float* __restrict__ ph1,
                      const float* __restrict__ Wlin, const float* __restrict__ blin,
                      const float* __restrict__ ci_acc, const float* __restrict__ co_acc,
                      float* __restrict__ cins, float* __restrict__ couts,
                      float* __restrict__ logp) {
  __shared__ float jk[Dd];
  __shared__ float lg[Cc];
  int n = blockIdx.x, t = threadIdx.x;
  if (t == 63) {
    cins[n] = ci_acc[n] * (1.0f / (float)(Ll * Rr));
    couts[n] = co_acc[n] * (1.0f / (float)(Ll * Rr));
  }
  for (int d = t; d < Dd; d += 64) jk[d] = fmaxf(ph0[(size_t)n * Dd + d], ph1[(size_t)n * Dd + d]);
  __syncthreads();
  if (t < Cc) {
    float acc = blin[t];
    for (int k = 0; k < Dd; k++) acc += jk[k] * Wlin[k * Cc + t];
    lg[t] = acc;
  }
  __syncthreads();
  float m = -1e30f;
  for (int c = 0; c < Cc; c++) m = fmaxf(m, lg[c]);
  float s = 0.f;
  for (int c = 0; c < Cc; c++) s += expf(lg[c] - m);
  float lse = m + logf(s);
  if (t < Cc) logp[(size_t)n * Cc + t] = lg[t] - lse;
}

// ---------------- host ----------------
extern "C" void kernel_launch(void* const* d_in, const int* in_sizes, int n_in,
                              void* d_out, int out_size, void* d_ws, size_t ws_size,
                              hipStream_t stream) {
  const float* x      = (const float*)d_in[0];
  const int*   ei     = (const int*)d_in[1];
  const float* W_src  = (const float*)d_in[2];
  const float* b_src  = (const float*)d_in[3];
  const float* W_dst  = (const float*)d_in[4];
  const float* b_dst  = (const float*)d_in[5];
  const float* W_outf = (const float*)d_in[6];
  const float* b_outf = (const float*)d_in[7];
  const float* W_inf  = (const float*)d_in[8];
  const float* b_inf  = (const float*)d_in[9];
  const float* W_fc   = (const float*)d_in[10];
  const float* b_fc   = (const float*)d_in[11];
  const float* gamma  = (const float*)d_in[12];
  const float* beta   = (const float*)d_in[13];
  const float* oemb   = (const float*)d_in[14];
  const float* iemb   = (const float*)d_in[15];
  const float* omask  = (const float*)d_in[16];
  const float* omaskb = (const float*)d_in[17];
  const float* imask  = (const float*)d_in[18];
  const float* imaskb = (const float*)d_in[19];
  const float* alphap = (const float*)d_in[20];
  const float* taup   = (const float*)d_in[21];
  const float* Wlin   = (const float*)d_in[22];
  const float* blin   = (const float*)d_in[23];

  float* out   = (float*)d_out;
  float* logp  = out;
  float* cins  = logp + (size_t)Nn * Cc;
  float* couts = cins + Nn;
  float* ph0   = couts + Nn;
  float* ph1   = ph0 + (size_t)Nn * Dd;
  float* nh0   = ph1 + (size_t)Nn * Dd;
  float* nh1   = nh0 + (size_t)Nn * Dd;
  float* gs0   = nh1 + (size_t)Nn * Dd;
  float* gs1   = gs0 + Dd;

  char* p = (char*)d_ws;
  auto alloc = [&](size_t bytes) -> void* {
    void* q = (void*)p;
    p += (bytes + 255) & ~(size_t)255;
    return q;
  };
  float* pre2  = (float*)alloc((size_t)2 * Nn * Dd * 4);
  float* Tout2 = (float*)alloc((size_t)2 * Nn * Dd * 4);
  float* Tin2  = (float*)alloc((size_t)2 * Nn * Dd * 4);
  float* hperm = (float*)alloc((size_t)Nn * Dd * 4);
  unsigned* pbuf = (unsigned*)alloc((size_t)6 * Ee * 4);
  size_t qwords = (size_t)6 * Ee;
  size_t pwords = (size_t)(6 * 3 * HR_SB) * HR_PAD;
  unsigned* qbuf = (unsigned*)alloc((qwords > pwords ? qwords : pwords) * 4);
  int* partials = (int*)qbuf;
  int* csr_off = (int*)alloc((size_t)Rr * (Nn + 1) * 4);
  int* csc_off = (int*)alloc((size_t)Rr * (Nn + 1) * 4);
  int* odeg    = (int*)alloc((size_t)Rr * Nn * 4);
  int* ideg    = (int*)alloc((size_t)Rr * Nn * 4);
  float* ods   = (float*)alloc((size_t)Rr * Nn * 4);
  float* ids   = (float*)alloc((size_t)Rr * Nn * 4);
  int* odix    = (int*)alloc((size_t)Rr * Nn * 4);
  int* idix    = (int*)alloc((size_t)Rr * Nn * 4);
  float4* aux2 = (float4*)alloc((size_t)2 * Nn * 16);
  float4* auxrd2 = (float4*)alloc((size_t)2 * 6 * Nn * 16);
  float* sco2  = (float*)alloc((size_t)2 * Nn * 4);
  float* sci2  = (float*)alloc((size_t)2 * Nn * 4);
  float* coacc = (float*)alloc((size_t)Nn * 4 * 2);
  float* ciacc = coacc + Nn;
  float* luto  = (float*)alloc((size_t)2 * MAXD * 4);
  float* luti  = (float*)alloc((size_t)2 * MAXD * 4);
  float* bnsum2 = (float*)alloc(512 * 4);
  unsigned* kbuf0 = (unsigned*)alloc((size_t)2 * Nn * 4);
  unsigned* kbuf1 = (unsigned*)alloc((size_t)2 * Nn * 4);
  int* vbuf0 = (int*)alloc((size_t)2 * Nn * 4);
  int* vbuf1 = (int*)alloc((size_t)2 * Nn * 4);
  int* rhist = (int*)alloc((size_t)2 * (RB_H + 1) * 4);
  int* rscan = (int*)alloc((size_t)2 * (RB_H + 1) * 4);
  int* ehist = (int*)alloc((size_t)6 * EB_H * 4);
  int* escan = (int*)alloc((size_t)6 * (EB_H + 1) * 4);

  // ---- graph structure ----
  k_hist2<<<6 * 3 * HR_SB, 256, 0, stream>>>(ei, partials);
  k_hreduce<<<(6 * Nn + 255) / 256, 256, 0, stream>>>(partials, odeg, ideg);
  k_degnorm<<<(Rr * Nn + 255) / 256, 256, 0, stream>>>(odeg, ideg, ods, ids, odix, idix);
  k_scan6<<<6, 1024, 0, stream>>>(odeg, ideg, csr_off, csc_off);
  k_pack<<<(3 * Ee + 255) / 256, 256, 0, stream>>>(ei, pbuf, pbuf + (size_t)3 * Ee);
  k_ehist<<<6 * EB_NB, 256, 0, stream>>>(pbuf, ehist, 16);
  k_escan6<<<6, 1024, 0, stream>>>(ehist, escan);
  k_escatter<<<6 * EB_NB, 256, 0, stream>>>(pbuf, escan, 16, qbuf);
  k_ehist<<<6 * EB_NB, 256, 0, stream>>>(qbuf, ehist, 24);
  k_escan6<<<6, 1024, 0, stream>>>(ehist, escan);
  k_escatter<<<6 * EB_NB, 256, 0, stream>>>(qbuf, escan, 24, pbuf);
  hipMemsetAsync(coacc, 0, (size_t)Nn * 4 * 2, stream);
  k_lut2<<<2 * MAXD / 4, 256, 0, stream>>>(oemb, iemb, W_outf, W_inf, luto, luti);

  // ---- both permutations, batched (seeds 100 & 101) ----
  auto radix4b = [&]() {
    for (int pass = 0; pass < 4; pass++) {
      const unsigned* ik = (pass & 1) ? kbuf1 : kbuf0;
      const int*      iv = (pass & 1) ? vbuf1 : vbuf0;
      unsigned*       ok = (pass & 1) ? kbuf0 : kbuf1;
      int*            ov = (pass & 1) ? vbuf0 : vbuf1;
      int shift = pass * 8;
      k_rhist2<<<2 * RB_NB, 256, 0, stream>>>(ik, rhist, shift);
      k_scanP<<<2, 1024, 0, stream>>>(rhist, rscan);
      k_rscatter2<<<2 * RB_NB, 256, 0, stream>>>(ik, iv, rscan, shift, ok, ov);
    }
  };
  k_genkeys2<<<(2 * Nn + 255) / 256, 256, 0, stream>>>(kbuf0, 100u, 101u, 1, vbuf0, 1);
  radix4b();
  k_genkeys2<<<(2 * Nn + 255) / 256, 256, 0, stream>>>(kbuf0, 100u, 101u, 2, vbuf0, 0);
  radix4b();

  // biconv: pos (hA -> houtA) and neg (hB -> houtB) batched per layer
  auto biconv = [&](int l, const float* hA, const float* hB,
                    float* houtA, float* houtB, float* gs) {
    const float* Wfo = W_outf + l * Dd;
    const float* Wfi = W_inf + l * Dd;
    k_rowscalar<<<2 * (Nn / 4), 256, 0, stream>>>(hA, hB, Wfo, Wfi, aux2, ods, ids, auxrd2,
                                                  bnsum2, gs);
    for (int r = 0; r < Rr; r++) {
      k_csrdir3<<<2 * (Nn / 2), 256, 0, stream>>>(csr_off + r * (Nn + 1), pbuf + (size_t)r * Ee,
                                                  csc_off + r * (Nn + 1), pbuf + (size_t)(3 + r) * Ee,
                                                  ods + r * Nn, ids + r * Nn,
                                                  auxrd2, r, aux2, hA, hB, Wfo, Wfi,
                                                  luto + l * MAXD, luti + l * MAXD,
                                                  odix + r * Nn, idix + r * Nn,
                                                  b_outf + l, b_inf + l, taup,
                                                  omask + (size_t)r * Nn, omaskb + (size_t)r * Nn,
                                                  imask + (size_t)r * Nn, imaskb + (size_t)r * Nn,
                                                  Tout2, Tin2, sco2, sci2, coacc, ciacc,
                                                  r == 0 ? 1 : 0);
    }
    k_gemmconv<<<2 * (Nn / 64), 256, 0, stream>>>(Tout2, Tin2, hA, hB,
                                                  W_src + (size_t)l * Dd * Dd,
                                                  W_dst + (size_t)l * Dd * Dd,
                                                  W_fc + (size_t)l * Dd * Dd,
                                                  b_src + l * Dd, b_dst + l * Dd, b_fc + l * Dd,
                                                  sco2, sci2, alphap, pre2, bnsum2);
    k_bnapply<<<512, 256, 0, stream>>>(pre2, bnsum2, gamma + l * Dd, beta + l * Dd,
                                       houtA, houtB, gs);
  };

  // ---- layer 0 ----
  k_permrows<<<Nn / 8, 256, 0, stream>>>(x, vbuf0, hperm);
  biconv(0, x, hperm, ph0, nh0, gs0);

  // ---- layer 1 ----
  k_permrows<<<Nn / 8, 256, 0, stream>>>(nh0, vbuf0 + Nn, hperm);
  biconv(1, ph0, hperm, ph1, nh1, gs1);

  // ---- outputs ----
  k_logp<<<Nn, 64, 0, stream>>>(ph0, ph1, Wlin, blin, ciacc, coacc, cins, couts, logp);
}